// Round 8
// baseline (10481.380 us; speedup 1.0000x reference)
//
#include <hip/hip_runtime.h>

#define TOK   8192
#define DD    1024
#define FF    4096
#define EE    8
#define TWOF  8192
#define NSLOT 16384   // TOK * top_k(2)
#define PADT  18432   // NSLOT + 8*256 (per-expert 256-row padding bound)

typedef unsigned short u16;
typedef float  f32x16 __attribute__((ext_vector_type(16)));
typedef __bf16 bf16x8 __attribute__((ext_vector_type(8)));

__device__ __forceinline__ u16 f2b(float f) {
  unsigned u = __builtin_bit_cast(unsigned, f);
  u += 0x7fffu + ((u >> 16) & 1u);   // RNE; inputs finite
  return (u16)(u >> 16);
}

__device__ __forceinline__ void ldslds16(const void* g, void* l) {
  __builtin_amdgcn_global_load_lds((const __attribute__((address_space(1))) void*)g,
                                   (__attribute__((address_space(3))) void*)l, 16, 0, 0);
}

// ---------------- gate: logits, softmax, top-2, counts ----------------
__global__ void gate_kernel(const float* __restrict__ x, const float* __restrict__ gw,
                            const float* __restrict__ gb, int* __restrict__ counts,
                            int* __restrict__ eidx, int* __restrict__ epos,
                            float* __restrict__ ew) {
  const int wave = threadIdx.x >> 6, lane = threadIdx.x & 63;
  const int t = blockIdx.x * 4 + wave;
  float acc[EE] = {0,0,0,0,0,0,0,0};
  const float* xr = x + (size_t)t * DD;
  for (int d = lane; d < DD; d += 64) {
    float xv = xr[d];
    const float* g = gw + (size_t)d * EE;
#pragma unroll
    for (int e = 0; e < EE; ++e) acc[e] += xv * g[e];
  }
#pragma unroll
  for (int e = 0; e < EE; ++e)
#pragma unroll
    for (int off = 32; off > 0; off >>= 1) acc[e] += __shfl_down(acc[e], off);
  if (lane == 0) {
    float l[EE];
#pragma unroll
    for (int e = 0; e < EE; ++e) l[e] = acc[e] + gb[e];
    int i0 = 0;
    for (int e = 1; e < EE; ++e) if (l[e] > l[i0]) i0 = e;
    int i1 = (i0 == 0) ? 1 : 0;
    for (int e = 0; e < EE; ++e) { if (e == i0) continue; if (l[e] > l[i1]) i1 = e; }
    float m = l[0];
    for (int e = 1; e < EE; ++e) m = fmaxf(m, l[e]);
    float s = 0.f, p[EE];
    for (int e = 0; e < EE; ++e) { p[e] = __expf(l[e] - m); s += p[e]; }
    float w0 = p[i0] / s, w1 = p[i1] / s;
    int p0 = atomicAdd(&counts[i0], 1);
    int p1 = atomicAdd(&counts[i1], 1);
    eidx[2*t] = i0; eidx[2*t+1] = i1;
    epos[2*t] = p0; epos[2*t+1] = p1;
    ew[2*t] = w0;  ew[2*t+1] = w1;
  }
}

// setup: meta[0..7]=opad (256-aligned expert slot offsets), meta[8..16]=tm-block prefix
__global__ void setup_kernel(const int* __restrict__ counts, int* __restrict__ meta) {
  if (threadIdx.x == 0 && blockIdx.x == 0) {
    int s = 0, tm = 0;
    for (int e = 0; e < EE; ++e) {
      meta[e] = s;
      meta[8 + e] = tm;
      s  += (counts[e] + 255) & ~255;
      tm += (counts[e] + 255) >> 8;
    }
    meta[16] = tm;
  }
}

__global__ void slot_kernel(const int* __restrict__ eidx, const int* __restrict__ epos,
                            const float* __restrict__ ew, const int* __restrict__ meta,
                            int* __restrict__ s2t, float* __restrict__ swt,
                            int* __restrict__ t2s) {
  int i = blockIdx.x * 256 + threadIdx.x;           // 0..2T-1
  int e = eidx[i];
  int slot = meta[e] + epos[i];
  s2t[slot] = i >> 1;
  swt[slot] = ew[i];
  t2s[i] = slot;
}

// ---------------- conversions ----------------
__global__ void cvtx_kernel(const float* __restrict__ x, u16* __restrict__ xb) {
  int i = blockIdx.x * 256 + threadIdx.x;           // 4 elements each
  float4 v = ((const float4*)x)[i];
  unsigned lo = (unsigned)f2b(v.x) | ((unsigned)f2b(v.y) << 16);
  unsigned hi = (unsigned)f2b(v.z) | ((unsigned)f2b(v.w) << 16);
  ((uint2*)xb)[i] = make_uint2(lo, hi);
}

__global__ void gather_kernel(const u16* __restrict__ xb, const int* __restrict__ s2t,
                              u16* __restrict__ xg) {
  int i = blockIdx.x * 256 + threadIdx.x;           // 16B chunks, PADT rows
  int row = i >> 7, c = i & 127;
  int tok = s2t[row];                                // pad slots are 0 (memset)
  ((int4*)xg)[(size_t)row * 128 + c] = ((const int4*)xb)[(size_t)tok * 128 + c];
}

// transpose-convert weights: dst[seg][n][k] (bf16) = src[seg][k][oc(n)] (f32)
// permute (w1 only): interleave a/b halves in 32-col groups (SwiGLU pairing, 32x32 MFMA)
__global__ void wt_kernel(const float* __restrict__ srcS, const float* __restrict__ srcR,
                          u16* __restrict__ dst, int K, int N, int permute) {
  __shared__ float tile[32][33];
  const int seg = blockIdx.z;
  const float* src = (seg == 0) ? srcS : srcR + (size_t)(seg - 1) * K * N;
  const int pc0 = blockIdx.x * 32, k0 = blockIdx.y * 32;
  const int tid = threadIdx.x;
  {
    int kk = tid >> 3, j4 = (tid & 7) << 2;
    const float* srow = src + (size_t)(k0 + kk) * N;
#pragma unroll
    for (int q = 0; q < 4; ++q) {
      int n = pc0 + j4 + q;
      int oc = permute ? (((n >> 6) << 5) + (n & 31) + ((n & 32) ? FF : 0)) : n;
      tile[kk][j4 + q] = srow[oc];
    }
  }
  __syncthreads();
  {
    int pp = tid >> 3, kq = (tid & 7) << 2;
    u16* drow = dst + (size_t)seg * N * K + (size_t)(pc0 + pp) * K + k0 + kq;
#pragma unroll
    for (int q = 0; q < 4; ++q) drow[q] = f2b(tile[kq + q][pp]);
  }
}

// ================= 256x256x64 single-buffer GEMM core =================
// 8 waves (2M x 4N), per-wave 128x64 (4x2 frags of 32x32x16). LDS 64 KiB ->
// 2 blocks/CU (implicit cross-block overlap per m114). Per-wave per ks:
// 6 LDS reads feed 8 MFMAs (768 B/MFMA vs 1024 in the 128^2 tile).
// Swizzle byte col ^= (row&7)<<4 applied both sides (gload source + ds_read).

template<int NT>
__device__ __forceinline__ void core256(
    const char* Aseg, long long lda, long long arow0,
    const char* Bseg, long long ldb, long long bcol0,
    char* lds, int tid, f32x16 (&acc)[4][2]) {
  const int lane = tid & 63, wid = tid >> 6;
  const int wm = wid >> 2, wn = wid & 3;
  const int l31 = lane & 31, kg = (lane >> 5) * 16;
  const int C = (l31 & 7) << 4;
  int kcol[4];
#pragma unroll
  for (int ks = 0; ks < 4; ++ks) kcol[ks] = (ks * 32 + kg) ^ C;
  int aoff[4], boff[2];
#pragma unroll
  for (int mf = 0; mf < 4; ++mf) aoff[mf] = (wm * 128 + mf * 32 + l31) * 128;
#pragma unroll
  for (int nf = 0; nf < 2; ++nf) boff[nf] = 32768 + (wn * 64 + nf * 32 + l31) * 128;

  const int srow = tid >> 3, schunk = (tid & 7) * 16;
  const char* gsA[4]; const char* gsB[4];
#pragma unroll
  for (int s = 0; s < 4; ++s) {
    int rloc = s * 64 + srow;
    int sw = schunk ^ ((rloc & 7) << 4);
    gsA[s] = Aseg + (arow0 + rloc) * lda + sw;
    gsB[s] = Bseg + (bcol0 + rloc) * ldb + sw;
  }

  for (int it = 0; it < NT; ++it) {
    const long long kb = (long long)it * 128;        // 64 u16 per iter
#pragma unroll
    for (int s = 0; s < 4; ++s) ldslds16(gsA[s] + kb, lds + s * 8192 + tid * 16);
#pragma unroll
    for (int s = 0; s < 4; ++s) ldslds16(gsB[s] + kb, lds + 32768 + s * 8192 + tid * 16);
    __syncthreads();
#pragma unroll
    for (int ks = 0; ks < 4; ++ks) {
      bf16x8 af[4], bq[2];
#pragma unroll
      for (int mf = 0; mf < 4; ++mf) af[mf] = *(const bf16x8*)(lds + aoff[mf] + kcol[ks]);
#pragma unroll
      for (int nf = 0; nf < 2; ++nf) bq[nf] = *(const bf16x8*)(lds + boff[nf] + kcol[ks]);
#pragma unroll
      for (int mf = 0; mf < 4; ++mf)
#pragma unroll
        for (int nf = 0; nf < 2; ++nf)
          acc[mf][nf] = __builtin_amdgcn_mfma_f32_32x32x16_bf16(af[mf], bq[nf], acc[mf][nf], 0, 0, 0);
    }
    __syncthreads();
  }
}

// map compact g -> (seg, tm, rowstart, rows)
__device__ __forceinline__ bool seg_map(int g, const int* __restrict__ counts,
                                        const int* __restrict__ meta,
                                        int& seg, int& tm, int& rowstart, int& rows) {
  if (g < 32) { seg = 0; tm = g; rowstart = 0; rows = TOK; return true; }
  int gr = g - 32;
  if (gr >= meta[16]) return false;
  int e = 0;
  while (gr >= meta[8 + e + 1]) ++e;
  seg = e + 1; tm = gr - meta[8 + e];
  rowstart = meta[e]; rows = counts[e];
  return true;
}

// ---------------- GEMM1: x @ w1t(permuted) -> SwiGLU -> hs bf16 ----------------
__global__ __launch_bounds__(512, 4)
void gemm1_kernel(const u16* __restrict__ xb, const u16* __restrict__ xg,
                  const u16* __restrict__ w1t, const float* __restrict__ sb1,
                  const float* __restrict__ rb1, const int* __restrict__ counts,
                  const int* __restrict__ meta, u16* __restrict__ hs) {
  __shared__ __align__(16) char lds[65536];
  // XCD chunking: XCD = lin&7 owns tn in [4x, 4x+4) -> B working set 2 MB (L2-fit)
  const int lin = blockIdx.x + 32 * blockIdx.y;
  const int tn = (lin & 7) * 4 + ((lin >> 3) & 3);
  const int g = lin >> 5;
  int seg, tm, rowstart, rows;
  if (!seg_map(g, counts, meta, seg, tm, rowstart, rows)) return;
  const u16* A = (seg == 0) ? xb : xg;
  const int hsbase = (seg == 0) ? 0 : TOK + rowstart;
  const int tid = threadIdx.x, lane = tid & 63, wid = tid >> 6;
  const int wm = wid >> 2, wn = wid & 3;

  f32x16 acc[4][2] = {};
  core256<DD / 64>((const char*)A, DD * 2, rowstart + (long long)tm * 256,
                   (const char*)(w1t + (size_t)seg * TWOF * DD), DD * 2,
                   (long long)tn * 256, lds, tid, acc);

  const int l31 = lane & 31, lg = lane >> 5;
  const int rlim = rows - tm * 256;
  const float* b1 = (seg == 0) ? sb1 : rb1 + (size_t)(seg - 1) * TWOF;
  const int f = (tn * 4 + wn) * 32 + l31;
  const float ba = b1[f], bb = b1[FF + f];
  u16* hbase = hs + (size_t)(hsbase + tm * 256) * FF;
#pragma unroll
  for (int mf = 0; mf < 4; ++mf)
#pragma unroll
    for (int reg = 0; reg < 16; ++reg) {
      int lr = wm * 128 + mf * 32 + (reg & 3) + 8 * (reg >> 2) + 4 * lg;
      if (lr < rlim) {
        float av = acc[mf][0][reg] + ba;
        float bv = acc[mf][1][reg] + bb;
        float sv = av / (1.0f + __expf(-av)) * bv;
        hbase[(size_t)lr * FF + f] = f2b(sv);
      }
    }
}

// ---------------- GEMM2: hs @ w2t -> yo (f32, all segments, no atomics) ----------------
__global__ __launch_bounds__(512, 4)
void gemm2_kernel(const u16* __restrict__ hs, const u16* __restrict__ w2t,
                  const float* __restrict__ sb2, const float* __restrict__ rb2,
                  const int* __restrict__ counts, const int* __restrict__ meta,
                  float* __restrict__ yo) {
  __shared__ __align__(16) char lds[65536];
  const int lin = blockIdx.x + 4 * blockIdx.y;
  const int tn = lin & 3;                           // 2 XCDs share each 2MB B panel
  const int g = lin >> 2;
  int seg, tm, rowstart, rows;
  if (!seg_map(g, counts, meta, seg, tm, rowstart, rows)) return;
  const int hrow0 = (seg == 0) ? 0 : TOK + rowstart;
  const int tid = threadIdx.x, lane = tid & 63, wid = tid >> 6;
  const int wm = wid >> 2, wn = wid & 3;

  f32x16 acc[4][2] = {};
  core256<FF / 64>((const char*)hs, FF * 2, hrow0 + (long long)tm * 256,
                   (const char*)(w2t + (size_t)seg * DD * FF), FF * 2,
                   (long long)tn * 256, lds, tid, acc);

  const int l31 = lane & 31, lg = lane >> 5;
  const int rlim = rows - tm * 256;
  const float* b2 = (seg == 0) ? sb2 : rb2 + (size_t)(seg - 1) * DD;
  const int c0 = tn * 256 + wn * 64 + l31;
  const float bias0 = b2[c0], bias1 = b2[c0 + 32];
  float* ybase = yo + (size_t)(hrow0 + tm * 256) * DD;
#pragma unroll
  for (int mf = 0; mf < 4; ++mf)
#pragma unroll
    for (int reg = 0; reg < 16; ++reg) {
      int lr = wm * 128 + mf * 32 + (reg & 3) + 8 * (reg >> 2) + 4 * lg;
      if (lr < rlim) {
        float* orow = ybase + (size_t)lr * DD;
        orow[c0]      = acc[mf][0][reg] + bias0;
        orow[c0 + 32] = acc[mf][1][reg] + bias1;
      }
    }
}

// ---------------- combine: out[t] = yo[t] + w0*yo[T+s0] + w1*yo[T+s1] ----------------
__global__ void combine_kernel(const float* __restrict__ yo, const int* __restrict__ t2s,
                               const float* __restrict__ ew, float* __restrict__ out) {
  const int t = blockIdx.x, d = threadIdx.x;   // 256 threads x 4 floats
  const float4 a  = ((const float4*)(yo + (size_t)t * DD))[d];
  const int s0 = t2s[2*t], s1 = t2s[2*t+1];
  const float w0 = ew[2*t], w1 = ew[2*t+1];
  const float4 r0 = ((const float4*)(yo + (size_t)(TOK + s0) * DD))[d];
  const float4 r1 = ((const float4*)(yo + (size_t)(TOK + s1) * DD))[d];
  float4 r;
  r.x = a.x + w0 * r0.x + w1 * r1.x;
  r.y = a.y + w0 * r0.y + w1 * r1.y;
  r.z = a.z + w0 * r0.z + w1 * r1.z;
  r.w = a.w + w0 * r0.w + w1 * r1.w;
  ((float4*)(out + (size_t)t * DD))[d] = r;
}

// ---------------- launch ----------------
extern "C" void kernel_launch(void* const* d_in, const int* in_sizes, int n_in,
                              void* d_out, int out_size, void* d_ws, size_t ws_size,
                              hipStream_t stream) {
  const float* x   = (const float*)d_in[0];
  const float* gw  = (const float*)d_in[1];
  const float* gb  = (const float*)d_in[2];
  const float* sw1 = (const float*)d_in[3];
  const float* sb1 = (const float*)d_in[4];
  const float* sw2 = (const float*)d_in[5];
  const float* sb2 = (const float*)d_in[6];
  const float* rw1 = (const float*)d_in[7];
  const float* rb1 = (const float*)d_in[8];
  const float* rw2 = (const float*)d_in[9];
  const float* rb2 = (const float*)d_in[10];
  float* out = (float*)d_out;

  char* p = (char*)d_ws;
  auto alloc = [&](size_t bytes) { char* r = p; p += (bytes + 255) & ~(size_t)255; return r; };
  int*   counts = (int*)alloc(EE * 4);
  int*   meta   = (int*)alloc(17 * 4);
  int*   eidx   = (int*)alloc((size_t)2 * TOK * 4);
  int*   epos   = (int*)alloc((size_t)2 * TOK * 4);
  float* ew     = (float*)alloc((size_t)2 * TOK * 4);
  int*   s2t    = (int*)alloc((size_t)PADT * 4);
  float* swt    = (float*)alloc((size_t)PADT * 4);
  int*   t2s    = (int*)alloc((size_t)2 * TOK * 4);
  u16*   xb     = (u16*)alloc((size_t)TOK * DD * 2);
  u16*   xg     = (u16*)alloc((size_t)PADT * DD * 2);
  u16*   w1t    = (u16*)alloc((size_t)9 * TWOF * DD * 2);
  u16*   w2t    = (u16*)alloc((size_t)9 * DD * FF * 2);
  u16*   hs     = (u16*)alloc((size_t)(TOK + PADT + 256) * FF * 2);
  // yo aliases w1t: gemm2 runs strictly after gemm1 (same stream); ~110MB <= 151MB
  float* yo     = (float*)w1t;

  hipMemsetAsync(counts, 0, EE * 4, stream);
  hipMemsetAsync(s2t, 0, (size_t)PADT * 4, stream);
  gate_kernel<<<TOK / 4, 256, 0, stream>>>(x, gw, gb, counts, eidx, epos, ew);
  setup_kernel<<<1, 64, 0, stream>>>(counts, meta);
  slot_kernel<<<(2 * TOK) / 256, 256, 0, stream>>>(eidx, epos, ew, meta, s2t, swt, t2s);
  cvtx_kernel<<<(TOK * DD / 4) / 256, 256, 0, stream>>>(x, xb);
  gather_kernel<<<PADT / 2, 256, 0, stream>>>(xb, s2t, xg);
  wt_kernel<<<dim3(TWOF / 32, DD / 32, 9), 256, 0, stream>>>(sw1, rw1, w1t, DD, TWOF, 1);
  wt_kernel<<<dim3(DD / 32, FF / 32, 9), 256, 0, stream>>>(sw2, rw2, w2t, FF, DD, 0);
  gemm1_kernel<<<dim3(32, 104), 512, 0, stream>>>(xb, xg, w1t, sb1, rb1, counts, meta, hs);
  gemm2_kernel<<<dim3(4, 104), 512, 0, stream>>>(hs, w2t, sb2, rb2, counts, meta, yo);
  combine_kernel<<<TOK, 256, 0, stream>>>(yo, t2s, ew, out);
}

// Round 9
// 1253.478 us; speedup vs baseline: 8.3618x; 8.3618x over previous
//
#include <hip/hip_runtime.h>

#define TOK   8192
#define DD    1024
#define FF    4096
#define EE    8
#define TWOF  8192
#define NSLOT 16384   // TOK * top_k(2)
#define PADT  18432   // NSLOT + 8*256 (per-expert 256-row padding bound)

typedef unsigned short u16;
typedef float  f32x16 __attribute__((ext_vector_type(16)));
typedef __bf16 bf16x8 __attribute__((ext_vector_type(8)));

__device__ __forceinline__ u16 f2b(float f) {
  unsigned u = __builtin_bit_cast(unsigned, f);
  u += 0x7fffu + ((u >> 16) & 1u);   // RNE; inputs finite
  return (u16)(u >> 16);
}

__device__ __forceinline__ void ldslds16(const void* g, void* l) {
  __builtin_amdgcn_global_load_lds((const __attribute__((address_space(1))) void*)g,
                                   (__attribute__((address_space(3))) void*)l, 16, 0, 0);
}

// ---------------- gate: logits, softmax, top-2, counts ----------------
__global__ void gate_kernel(const float* __restrict__ x, const float* __restrict__ gw,
                            const float* __restrict__ gb, int* __restrict__ counts,
                            int* __restrict__ eidx, int* __restrict__ epos,
                            float* __restrict__ ew) {
  const int wave = threadIdx.x >> 6, lane = threadIdx.x & 63;
  const int t = blockIdx.x * 4 + wave;
  float acc[EE] = {0,0,0,0,0,0,0,0};
  const float* xr = x + (size_t)t * DD;
  for (int d = lane; d < DD; d += 64) {
    float xv = xr[d];
    const float* g = gw + (size_t)d * EE;
#pragma unroll
    for (int e = 0; e < EE; ++e) acc[e] += xv * g[e];
  }
#pragma unroll
  for (int e = 0; e < EE; ++e)
#pragma unroll
    for (int off = 32; off > 0; off >>= 1) acc[e] += __shfl_down(acc[e], off);
  if (lane == 0) {
    float l[EE];
#pragma unroll
    for (int e = 0; e < EE; ++e) l[e] = acc[e] + gb[e];
    int i0 = 0;
    for (int e = 1; e < EE; ++e) if (l[e] > l[i0]) i0 = e;
    int i1 = (i0 == 0) ? 1 : 0;
    for (int e = 0; e < EE; ++e) { if (e == i0) continue; if (l[e] > l[i1]) i1 = e; }
    float m = l[0];
    for (int e = 1; e < EE; ++e) m = fmaxf(m, l[e]);
    float s = 0.f, p[EE];
    for (int e = 0; e < EE; ++e) { p[e] = __expf(l[e] - m); s += p[e]; }
    float w0 = p[i0] / s, w1 = p[i1] / s;
    int p0 = atomicAdd(&counts[i0], 1);
    int p1 = atomicAdd(&counts[i1], 1);
    eidx[2*t] = i0; eidx[2*t+1] = i1;
    epos[2*t] = p0; epos[2*t+1] = p1;
    ew[2*t] = w0;  ew[2*t+1] = w1;
  }
}

// setup: meta[0..7]=opad (256-aligned expert slot offsets), meta[8..16]=tm-block prefix
__global__ void setup_kernel(const int* __restrict__ counts, int* __restrict__ meta) {
  if (threadIdx.x == 0 && blockIdx.x == 0) {
    int s = 0, tm = 0;
    for (int e = 0; e < EE; ++e) {
      meta[e] = s;
      meta[8 + e] = tm;
      s  += (counts[e] + 255) & ~255;
      tm += (counts[e] + 255) >> 8;
    }
    meta[16] = tm;
  }
}

__global__ void slot_kernel(const int* __restrict__ eidx, const int* __restrict__ epos,
                            const float* __restrict__ ew, const int* __restrict__ meta,
                            int* __restrict__ s2t, float* __restrict__ swt,
                            int* __restrict__ t2s) {
  int i = blockIdx.x * 256 + threadIdx.x;           // 0..2T-1
  int e = eidx[i];
  int slot = meta[e] + epos[i];
  s2t[slot] = i >> 1;
  swt[slot] = ew[i];
  t2s[i] = slot;
}

// ---------------- conversions ----------------
__global__ void cvtx_kernel(const float* __restrict__ x, u16* __restrict__ xb) {
  int i = blockIdx.x * 256 + threadIdx.x;           // 4 elements each
  float4 v = ((const float4*)x)[i];
  unsigned lo = (unsigned)f2b(v.x) | ((unsigned)f2b(v.y) << 16);
  unsigned hi = (unsigned)f2b(v.z) | ((unsigned)f2b(v.w) << 16);
  ((uint2*)xb)[i] = make_uint2(lo, hi);
}

__global__ void gather_kernel(const u16* __restrict__ xb, const int* __restrict__ s2t,
                              u16* __restrict__ xg) {
  int i = blockIdx.x * 256 + threadIdx.x;           // 16B chunks, PADT rows
  int row = i >> 7, c = i & 127;
  int tok = s2t[row];                                // pad slots are 0 (memset)
  ((int4*)xg)[(size_t)row * 128 + c] = ((const int4*)xb)[(size_t)tok * 128 + c];
}

// transpose-convert weights: dst[seg][n][k] (bf16) = src[seg][k][oc(n)] (f32)
// permute (w1 only): interleave a/b halves in 32-col groups (SwiGLU pairing, 32x32 MFMA)
__global__ void wt_kernel(const float* __restrict__ srcS, const float* __restrict__ srcR,
                          u16* __restrict__ dst, int K, int N, int permute) {
  __shared__ float tile[32][33];
  const int seg = blockIdx.z;
  const float* src = (seg == 0) ? srcS : srcR + (size_t)(seg - 1) * K * N;
  const int pc0 = blockIdx.x * 32, k0 = blockIdx.y * 32;
  const int tid = threadIdx.x;
  {
    int kk = tid >> 3, j4 = (tid & 7) << 2;
    const float* srow = src + (size_t)(k0 + kk) * N;
#pragma unroll
    for (int q = 0; q < 4; ++q) {
      int n = pc0 + j4 + q;
      int oc = permute ? (((n >> 6) << 5) + (n & 31) + ((n & 32) ? FF : 0)) : n;
      tile[kk][j4 + q] = srow[oc];
    }
  }
  __syncthreads();
  {
    int pp = tid >> 3, kq = (tid & 7) << 2;
    u16* drow = dst + (size_t)seg * N * K + (size_t)(pc0 + pp) * K + k0 + kq;
#pragma unroll
    for (int q = 0; q < 4; ++q) drow[q] = f2b(tile[kq + q][pp]);
  }
}

// ================= 256x128x64 single-buffer GEMM core =================
// 4 waves (2M x 2N), per-wave 128x64 (4x2 frags of 32x32x16). LDS 48 KiB ->
// 2 blocks/CU (launch_bounds(256,2): 256-reg cap, acc 128 AGPR + ~100 VGPR fits).
// Per ks the wave reads 6 KB feeding 8 MFMAs (768 B/MFMA vs 1024 at 64x64/wave).
// Swizzle byte col ^= (row&7)<<4 applied both sides (gload source + ds_read).

template<int NT>
__device__ __forceinline__ void core_gemm(
    const char* Aseg, long long lda, long long arow0,
    const char* Bseg, long long ldb, long long bcol0,
    char* lds, int tid, f32x16 (&acc)[4][2]) {
  const int lane = tid & 63, wid = tid >> 6;
  const int wm = wid >> 1, wn = wid & 1;
  const int l31 = lane & 31, kg = (lane >> 5) * 16;
  const int C = (l31 & 7) << 4;
  int kcol[4];
#pragma unroll
  for (int ks = 0; ks < 4; ++ks) kcol[ks] = (ks * 32 + kg) ^ C;
  int aoff[4], boff[2];
#pragma unroll
  for (int mf = 0; mf < 4; ++mf) aoff[mf] = (wm * 128 + mf * 32 + l31) * 128;
#pragma unroll
  for (int nf = 0; nf < 2; ++nf) boff[nf] = 32768 + (wn * 64 + nf * 32 + l31) * 128;

  const int srow = tid >> 3, schunk = (tid & 7) * 16;
  const int sw = schunk ^ ((srow & 7) << 4);       // rloc&7 == srow&7 (stride 32)
  const char* gsA[8]; const char* gsB[4];
#pragma unroll
  for (int s = 0; s < 8; ++s) gsA[s] = Aseg + (arow0 + s * 32 + srow) * lda + sw;
#pragma unroll
  for (int s = 0; s < 4; ++s) gsB[s] = Bseg + (bcol0 + s * 32 + srow) * ldb + sw;

  for (int it = 0; it < NT; ++it) {
    const long long kb = (long long)it * 128;        // 64 u16 per iter
#pragma unroll
    for (int s = 0; s < 8; ++s) ldslds16(gsA[s] + kb, lds + s * 4096 + tid * 16);
#pragma unroll
    for (int s = 0; s < 4; ++s) ldslds16(gsB[s] + kb, lds + 32768 + s * 4096 + tid * 16);
    __syncthreads();
#pragma unroll
    for (int ks = 0; ks < 4; ++ks) {
      bf16x8 af[4], bq[2];
#pragma unroll
      for (int mf = 0; mf < 4; ++mf) af[mf] = *(const bf16x8*)(lds + aoff[mf] + kcol[ks]);
#pragma unroll
      for (int nf = 0; nf < 2; ++nf) bq[nf] = *(const bf16x8*)(lds + boff[nf] + kcol[ks]);
#pragma unroll
      for (int mf = 0; mf < 4; ++mf)
#pragma unroll
        for (int nf = 0; nf < 2; ++nf)
          acc[mf][nf] = __builtin_amdgcn_mfma_f32_32x32x16_bf16(af[mf], bq[nf], acc[mf][nf], 0, 0, 0);
    }
    __syncthreads();
  }
}

// map compact g -> (seg, tm, rowstart, rows)
__device__ __forceinline__ bool seg_map(int g, const int* __restrict__ counts,
                                        const int* __restrict__ meta,
                                        int& seg, int& tm, int& rowstart, int& rows) {
  if (g < 32) { seg = 0; tm = g; rowstart = 0; rows = TOK; return true; }
  int gr = g - 32;
  if (gr >= meta[16]) return false;
  int e = 0;
  while (gr >= meta[8 + e + 1]) ++e;
  seg = e + 1; tm = gr - meta[8 + e];
  rowstart = meta[e]; rows = counts[e];
  return true;
}

// ---------------- GEMM1: x @ w1t(permuted) -> SwiGLU -> hs bf16 ----------------
__global__ __launch_bounds__(256, 2)
void gemm1_kernel(const u16* __restrict__ xb, const u16* __restrict__ xg,
                  const u16* __restrict__ w1t, const float* __restrict__ sb1,
                  const float* __restrict__ rb1, const int* __restrict__ counts,
                  const int* __restrict__ meta, u16* __restrict__ hs) {
  __shared__ __align__(16) char lds[49152];
  // XCD chunking: XCD = lin&7 owns 8 consecutive tn -> B working set 2 MB (L2-fit)
  const int lin = blockIdx.x + 64 * blockIdx.y;
  const int tn = (lin & 7) * 8 + ((lin >> 3) & 7);
  const int g = lin >> 6;
  int seg, tm, rowstart, rows;
  if (!seg_map(g, counts, meta, seg, tm, rowstart, rows)) return;
  const u16* A = (seg == 0) ? xb : xg;
  const int hsbase = (seg == 0) ? 0 : TOK + rowstart;
  const int tid = threadIdx.x, lane = tid & 63, wid = tid >> 6;
  const int wm = wid >> 1, wn = wid & 1;

  f32x16 acc[4][2] = {};
  core_gemm<DD / 64>((const char*)A, DD * 2, rowstart + (long long)tm * 256,
                     (const char*)(w1t + (size_t)seg * TWOF * DD), DD * 2,
                     (long long)tn * 128, lds, tid, acc);

  const int l31 = lane & 31, lg = lane >> 5;
  const int rlim = rows - tm * 256;
  const float* b1 = (seg == 0) ? sb1 : rb1 + (size_t)(seg - 1) * TWOF;
  const int f = (tn * 2 + wn) * 32 + l31;
  const float ba = b1[f], bb = b1[FF + f];
  u16* hbase = hs + (size_t)(hsbase + tm * 256) * FF;
#pragma unroll
  for (int mf = 0; mf < 4; ++mf)
#pragma unroll
    for (int reg = 0; reg < 16; ++reg) {
      int lr = wm * 128 + mf * 32 + (reg & 3) + 8 * (reg >> 2) + 4 * lg;
      if (lr < rlim) {
        float av = acc[mf][0][reg] + ba;
        float bv = acc[mf][1][reg] + bb;
        float sv = av / (1.0f + __expf(-av)) * bv;
        hbase[(size_t)lr * FF + f] = f2b(sv);
      }
    }
}

// ---------------- GEMM2: hs @ w2t -> yo (f32, all segments, no atomics) ----------------
__global__ __launch_bounds__(256, 2)
void gemm2_kernel(const u16* __restrict__ hs, const u16* __restrict__ w2t,
                  const float* __restrict__ sb2, const float* __restrict__ rb2,
                  const int* __restrict__ counts, const int* __restrict__ meta,
                  float* __restrict__ yo) {
  __shared__ __align__(16) char lds[49152];
  const int tn = blockIdx.x;                        // 8 tn -> 8 XCDs naturally (1MB panel)
  const int g = blockIdx.y;
  int seg, tm, rowstart, rows;
  if (!seg_map(g, counts, meta, seg, tm, rowstart, rows)) return;
  const int hrow0 = (seg == 0) ? 0 : TOK + rowstart;
  const int tid = threadIdx.x, lane = tid & 63, wid = tid >> 6;
  const int wm = wid >> 1, wn = wid & 1;

  f32x16 acc[4][2] = {};
  core_gemm<FF / 64>((const char*)hs, FF * 2, hrow0 + (long long)tm * 256,
                     (const char*)(w2t + (size_t)seg * DD * FF), FF * 2,
                     (long long)tn * 128, lds, tid, acc);

  const int l31 = lane & 31, lg = lane >> 5;
  const int rlim = rows - tm * 256;
  const float* b2 = (seg == 0) ? sb2 : rb2 + (size_t)(seg - 1) * DD;
  const int c0 = tn * 128 + wn * 64 + l31;
  const float bias0 = b2[c0], bias1 = b2[c0 + 32];
  float* ybase = yo + (size_t)(hrow0 + tm * 256) * DD;
#pragma unroll
  for (int mf = 0; mf < 4; ++mf)
#pragma unroll
    for (int reg = 0; reg < 16; ++reg) {
      int lr = wm * 128 + mf * 32 + (reg & 3) + 8 * (reg >> 2) + 4 * lg;
      if (lr < rlim) {
        float* orow = ybase + (size_t)lr * DD;
        orow[c0]      = acc[mf][0][reg] + bias0;
        orow[c0 + 32] = acc[mf][1][reg] + bias1;
      }
    }
}

// ---------------- combine: out[t] = yo[t] + w0*yo[T+s0] + w1*yo[T+s1] ----------------
__global__ void combine_kernel(const float* __restrict__ yo, const int* __restrict__ t2s,
                               const float* __restrict__ ew, float* __restrict__ out) {
  const int t = blockIdx.x, d = threadIdx.x;   // 256 threads x 4 floats
  const float4 a  = ((const float4*)(yo + (size_t)t * DD))[d];
  const int s0 = t2s[2*t], s1 = t2s[2*t+1];
  const float w0 = ew[2*t], w1 = ew[2*t+1];
  const float4 r0 = ((const float4*)(yo + (size_t)(TOK + s0) * DD))[d];
  const float4 r1 = ((const float4*)(yo + (size_t)(TOK + s1) * DD))[d];
  float4 r;
  r.x = a.x + w0 * r0.x + w1 * r1.x;
  r.y = a.y + w0 * r0.y + w1 * r1.y;
  r.z = a.z + w0 * r0.z + w1 * r1.z;
  r.w = a.w + w0 * r0.w + w1 * r1.w;
  ((float4*)(out + (size_t)t * DD))[d] = r;
}

// ---------------- launch ----------------
extern "C" void kernel_launch(void* const* d_in, const int* in_sizes, int n_in,
                              void* d_out, int out_size, void* d_ws, size_t ws_size,
                              hipStream_t stream) {
  const float* x   = (const float*)d_in[0];
  const float* gw  = (const float*)d_in[1];
  const float* gb  = (const float*)d_in[2];
  const float* sw1 = (const float*)d_in[3];
  const float* sb1 = (const float*)d_in[4];
  const float* sw2 = (const float*)d_in[5];
  const float* sb2 = (const float*)d_in[6];
  const float* rw1 = (const float*)d_in[7];
  const float* rb1 = (const float*)d_in[8];
  const float* rw2 = (const float*)d_in[9];
  const float* rb2 = (const float*)d_in[10];
  float* out = (float*)d_out;

  char* p = (char*)d_ws;
  auto alloc = [&](size_t bytes) { char* r = p; p += (bytes + 255) & ~(size_t)255; return r; };
  int*   counts = (int*)alloc(EE * 4);
  int*   meta   = (int*)alloc(17 * 4);
  int*   eidx   = (int*)alloc((size_t)2 * TOK * 4);
  int*   epos   = (int*)alloc((size_t)2 * TOK * 4);
  float* ew     = (float*)alloc((size_t)2 * TOK * 4);
  int*   s2t    = (int*)alloc((size_t)PADT * 4);
  float* swt    = (float*)alloc((size_t)PADT * 4);
  int*   t2s    = (int*)alloc((size_t)2 * TOK * 4);
  u16*   xb     = (u16*)alloc((size_t)TOK * DD * 2);
  u16*   xg     = (u16*)alloc((size_t)PADT * DD * 2);
  u16*   w1t    = (u16*)alloc((size_t)9 * TWOF * DD * 2);
  u16*   w2t    = (u16*)alloc((size_t)9 * DD * FF * 2);
  u16*   hs     = (u16*)alloc((size_t)(TOK + PADT + 256) * FF * 2);
  // yo aliases w1t: gemm2 runs strictly after gemm1 (same stream); ~110MB <= 151MB
  float* yo     = (float*)w1t;

  hipMemsetAsync(counts, 0, EE * 4, stream);
  hipMemsetAsync(s2t, 0, (size_t)PADT * 4, stream);
  gate_kernel<<<TOK / 4, 256, 0, stream>>>(x, gw, gb, counts, eidx, epos, ew);
  setup_kernel<<<1, 64, 0, stream>>>(counts, meta);
  slot_kernel<<<(2 * TOK) / 256, 256, 0, stream>>>(eidx, epos, ew, meta, s2t, swt, t2s);
  cvtx_kernel<<<(TOK * DD / 4) / 256, 256, 0, stream>>>(x, xb);
  gather_kernel<<<PADT / 2, 256, 0, stream>>>(xb, s2t, xg);
  wt_kernel<<<dim3(TWOF / 32, DD / 32, 9), 256, 0, stream>>>(sw1, rw1, w1t, DD, TWOF, 1);
  wt_kernel<<<dim3(DD / 32, FF / 32, 9), 256, 0, stream>>>(sw2, rw2, w2t, FF, DD, 0);
  gemm1_kernel<<<dim3(64, 104), 256, 0, stream>>>(xb, xg, w1t, sb1, rb1, counts, meta, hs);
  gemm2_kernel<<<dim3(8, 104), 256, 0, stream>>>(hs, w2t, sb2, rb2, counts, meta, yo);
  combine_kernel<<<TOK, 256, 0, stream>>>(yo, t2s, ew, out);
}

// Round 10
// 1228.973 us; speedup vs baseline: 8.5286x; 1.0199x over previous
//
#include <hip/hip_runtime.h>

#define TOK   8192
#define DD    1024
#define FF    4096
#define EE    8
#define TWOF  8192
#define NSLOT 16384   // TOK * top_k(2)
#define PADT  17408   // NSLOT + 8*128 (per-expert 128-row padding bound)

typedef unsigned short u16;
typedef float  f32x16 __attribute__((ext_vector_type(16)));
typedef __bf16 bf16x8 __attribute__((ext_vector_type(8)));

__device__ __forceinline__ u16 f2b(float f) {
  unsigned u = __builtin_bit_cast(unsigned, f);
  u += 0x7fffu + ((u >> 16) & 1u);   // RNE; inputs finite
  return (u16)(u >> 16);
}

__device__ __forceinline__ void ldslds16(const void* g, void* l) {
  __builtin_amdgcn_global_load_lds((const __attribute__((address_space(1))) void*)g,
                                   (__attribute__((address_space(3))) void*)l, 16, 0, 0);
}

// ---------------- gate (+x->bf16 convert fused): logits, softmax, top-2 ----------------
__global__ void gate_kernel(const float* __restrict__ x, const float* __restrict__ gw,
                            const float* __restrict__ gb, int* __restrict__ counts,
                            int* __restrict__ eidx, int* __restrict__ epos,
                            float* __restrict__ ew, u16* __restrict__ xb) {
  const int wave = threadIdx.x >> 6, lane = threadIdx.x & 63;
  const int t = blockIdx.x * 4 + wave;
  float acc[EE] = {0,0,0,0,0,0,0,0};
  const float* xr = x + (size_t)t * DD;
  u16* xbr = xb + (size_t)t * DD;
  for (int d = lane; d < DD; d += 64) {
    float xv = xr[d];
    xbr[d] = f2b(xv);                               // fused cvtx
    const float* g = gw + (size_t)d * EE;
#pragma unroll
    for (int e = 0; e < EE; ++e) acc[e] += xv * g[e];
  }
#pragma unroll
  for (int e = 0; e < EE; ++e)
#pragma unroll
    for (int off = 32; off > 0; off >>= 1) acc[e] += __shfl_down(acc[e], off);
  if (lane == 0) {
    float l[EE];
#pragma unroll
    for (int e = 0; e < EE; ++e) l[e] = acc[e] + gb[e];
    int i0 = 0;
    for (int e = 1; e < EE; ++e) if (l[e] > l[i0]) i0 = e;
    int i1 = (i0 == 0) ? 1 : 0;
    for (int e = 0; e < EE; ++e) { if (e == i0) continue; if (l[e] > l[i1]) i1 = e; }
    float m = l[0];
    for (int e = 1; e < EE; ++e) m = fmaxf(m, l[e]);
    float s = 0.f, p[EE];
    for (int e = 0; e < EE; ++e) { p[e] = __expf(l[e] - m); s += p[e]; }
    float w0 = p[i0] / s, w1 = p[i1] / s;
    int p0 = atomicAdd(&counts[i0], 1);
    int p1 = atomicAdd(&counts[i1], 1);
    eidx[2*t] = i0; eidx[2*t+1] = i1;
    epos[2*t] = p0; epos[2*t+1] = p1;
    ew[2*t] = w0;  ew[2*t+1] = w1;
  }
}

// slot: inline 128-aligned prefix over counts (8 ints, L2-hot)
__global__ void slot_kernel(const int* __restrict__ eidx, const int* __restrict__ epos,
                            const float* __restrict__ ew, const int* __restrict__ counts,
                            int* __restrict__ s2t, float* __restrict__ swt,
                            int* __restrict__ t2s) {
  int i = blockIdx.x * 256 + threadIdx.x;           // 0..2T-1
  int e = eidx[i];
  int off = 0;
  for (int j = 0; j < e; ++j) off += (counts[j] + 127) & ~127;
  int slot = off + epos[i];
  s2t[slot] = i >> 1;
  swt[slot] = ew[i];
  t2s[i] = slot;
}

// transpose-convert weights: dst[seg][n][k] (bf16) = src[seg][k][oc(n)] (f32)
// 64k x 64n tile per block; 16B vector reads and packed 16B bf16 writes.
// permute (w1 only): interleave a/b halves in 32-col groups (SwiGLU pairing)
__global__ void wt_kernel(const float* __restrict__ srcS, const float* __restrict__ srcR,
                          u16* __restrict__ dst, int K, int N, int permute) {
  __shared__ float tile[64][65];
  const int seg = blockIdx.z;
  const float* src = (seg == 0) ? srcS : srcR + (size_t)(seg - 1) * K * N;
  const int pc0 = blockIdx.x * 64, k0 = blockIdx.y * 64;
  const int tid = threadIdx.x;
  {
    int kk = tid >> 2, j0 = (tid & 3) * 16;
    const float* srow = src + (size_t)(k0 + kk) * N;
#pragma unroll
    for (int q = 0; q < 16; ++q) {
      int n = pc0 + j0 + q;
      int oc = permute ? (((n >> 6) << 5) + (n & 31) + ((n & 32) ? FF : 0)) : n;
      tile[kk][j0 + q] = srow[oc];
    }
  }
  __syncthreads();
  {
    int pp = tid & 63;
    u16* drow = dst + (size_t)seg * N * K + (size_t)(pc0 + pp) * K + k0;
#pragma unroll
    for (int h = 0; h < 2; ++h) {
      int kq = (tid >> 6) * 16 + h * 8;
      uint4 v;
      unsigned* pv = (unsigned*)&v;
#pragma unroll
      for (int q = 0; q < 4; ++q)
        pv[q] = (unsigned)f2b(tile[kq + 2*q][pp]) | ((unsigned)f2b(tile[kq + 2*q + 1][pp]) << 16);
      *(uint4*)(drow + kq) = v;
    }
  }
}

// ================= 128x128x64 GEMM core — 32x32x16 MFMA (R6-proven) =================
// 4 waves (2Mx2N), per-wave 64x64 (2x2 frags of 32x32). LDS 32 KiB -> ~4 blocks/CU.
// Swizzle byte col ^= (row&7)<<4 both sides (gload source + ds_read).

__device__ __forceinline__ void kloop32(int niter,
    const char* a0, const char* a1, const char* a2, const char* a3,
    const char* b0, const char* b1, const char* b2, const char* b3,
    u16* As, u16* Bs, int tid, f32x16 (&acc)[2][2]) {
  const int lane = tid & 63, l31 = lane & 31, kg = (lane >> 5) * 16;
  const int wid = tid >> 6, wm = wid >> 1, wn = wid & 1;
  const int C = (l31 & 7) << 4;
  const char* rA[4]; const char* rB[4];
#pragma unroll
  for (int ks = 0; ks < 4; ++ks) {        // 4 k-windows of 16 within BK=64
    const int o = (ks * 32 + kg) ^ C;
    rA[ks] = (const char*)As + (wm * 64 + l31) * 128 + o;
    rB[ks] = (const char*)Bs + (wn * 64 + l31) * 128 + o;
  }
  for (int it = 0; it < niter; ++it) {
    const long long kb = (long long)it * 128;        // 64 u16 per iter
    ldslds16(a0 + kb, As + tid * 8);
    ldslds16(a1 + kb, As + 2048 + tid * 8);
    ldslds16(a2 + kb, As + 4096 + tid * 8);
    ldslds16(a3 + kb, As + 6144 + tid * 8);
    ldslds16(b0 + kb, Bs + tid * 8);
    ldslds16(b1 + kb, Bs + 2048 + tid * 8);
    ldslds16(b2 + kb, Bs + 4096 + tid * 8);
    ldslds16(b3 + kb, Bs + 6144 + tid * 8);
    __syncthreads();
#pragma unroll
    for (int ks = 0; ks < 4; ++ks) {
      bf16x8 af0 = *(const bf16x8*)(rA[ks]);
      bf16x8 af1 = *(const bf16x8*)(rA[ks] + 4096);   // +32 rows
      bf16x8 bq0 = *(const bf16x8*)(rB[ks]);
      bf16x8 bq1 = *(const bf16x8*)(rB[ks] + 4096);
      acc[0][0] = __builtin_amdgcn_mfma_f32_32x32x16_bf16(af0, bq0, acc[0][0], 0, 0, 0);
      acc[0][1] = __builtin_amdgcn_mfma_f32_32x32x16_bf16(af0, bq1, acc[0][1], 0, 0, 0);
      acc[1][0] = __builtin_amdgcn_mfma_f32_32x32x16_bf16(af1, bq0, acc[1][0], 0, 0, 0);
      acc[1][1] = __builtin_amdgcn_mfma_f32_32x32x16_bf16(af1, bq1, acc[1][1], 0, 0, 0);
    }
    __syncthreads();
  }
}

// map compact g -> (seg, tm, rowstart, rows) scanning counts (no meta buffer)
__device__ __forceinline__ bool seg_map(int g, const int* __restrict__ counts,
                                        int& seg, int& tm, int& rowstart, int& rows) {
  if (g < 64) { seg = 0; tm = g; rowstart = 0; rows = TOK; return true; }
  int gr = g - 64, off = 0;
  for (int e = 0; e < EE; ++e) {
    int c = counts[e];
    int nb = (c + 127) >> 7;
    if (gr < nb) { seg = e + 1; tm = gr; rowstart = off; rows = c; return true; }
    gr -= nb;
    off += (c + 127) & ~127;
  }
  return false;
}

// ---------------- GEMM1: x @ w1t(permuted) -> SwiGLU -> hs bf16 ----------------
__global__ __launch_bounds__(256, 4)
void gemm1_kernel(const u16* __restrict__ xb, const int* __restrict__ s2t,
                  const u16* __restrict__ w1t, const float* __restrict__ sb1,
                  const float* __restrict__ rb1, const int* __restrict__ counts,
                  u16* __restrict__ hs) {
  __shared__ __align__(16) u16 As[128 * 64];
  __shared__ __align__(16) u16 Bs[128 * 64];
  // XCD L2 chunking: same tn -> same lin&7 -> same XCD; B-panel per XCD = 2 MB (L2-fit)
  const int lin = blockIdx.x + 64 * blockIdx.y;
  const int tn = (lin & 7) * 8 + ((lin >> 3) & 7);
  const int g = lin >> 6;
  int seg, tm, rowstart, rows;
  if (!seg_map(g, counts, seg, tm, rowstart, rows)) return;
  const int hsbase = (seg == 0) ? 0 : TOK + rowstart;
  const int tid = threadIdx.x, lane = tid & 63, wid = tid >> 6;
  const int wm = wid >> 1, wn = wid & 1;

  const int srow = tid >> 3;
  const int scol = ((tid & 7) * 16) ^ ((srow & 7) << 4);
  const char* Ac = (const char*)xb;
  const char* Bc = (const char*)(w1t + (size_t)seg * TWOF * DD);
  const char* a[4]; const char* b[4];
#pragma unroll
  for (int r = 0; r < 4; ++r) {
    int rbase = tm * 128 + r * 32 + srow;
    int rg = (seg == 0) ? rbase : s2t[rowstart + rbase];   // pad slots -> token 0
    a[r] = Ac + (size_t)rg * (DD * 2) + scol;
    b[r] = Bc + (size_t)(tn * 128 + r * 32 + srow) * (DD * 2) + scol;
  }

  f32x16 acc[2][2] = {};
  kloop32(DD / 64, a[0], a[1], a[2], a[3], b[0], b[1], b[2], b[3],
          As, Bs, tid, acc);

  const int l31 = lane & 31, lg = lane >> 5;
  const int rlim = rows - tm * 128;
  const float* b1 = (seg == 0) ? sb1 : rb1 + (size_t)(seg - 1) * TWOF;
  const int f = (tn * 2 + wn) * 32 + l31;
  const float ba = b1[f], bb = b1[FF + f];
  u16* hbase = hs + (size_t)(hsbase + tm * 128) * FF;
#pragma unroll
  for (int mi = 0; mi < 2; ++mi)
#pragma unroll
    for (int reg = 0; reg < 16; ++reg) {
      int lr = wm * 64 + mi * 32 + (reg & 3) + 8 * (reg >> 2) + 4 * lg;
      if (lr < rlim) {
        float av = acc[mi][0][reg] + ba;
        float bv = acc[mi][1][reg] + bb;
        float sv = av / (1.0f + __expf(-av)) * bv;
        hbase[(size_t)lr * FF + f] = f2b(sv);
      }
    }
}

// ---------------- GEMM2: hs @ w2t -> yo (f32, all segments, no atomics) ----------------
__global__ __launch_bounds__(256, 4)
void gemm2_kernel(const u16* __restrict__ hs, const u16* __restrict__ w2t,
                  const float* __restrict__ sb2, const float* __restrict__ rb2,
                  const int* __restrict__ counts, float* __restrict__ yo) {
  __shared__ __align__(16) u16 As[128 * 64];
  __shared__ __align__(16) u16 Bs[128 * 64];
  const int tn = blockIdx.x;                         // 8 tn -> block lin%8 -> XCD-affine
  const int g = blockIdx.y;
  int seg, tm, rowstart, rows;
  if (!seg_map(g, counts, seg, tm, rowstart, rows)) return;
  const int hrow0 = (seg == 0) ? 0 : TOK + rowstart;
  const int tid = threadIdx.x, lane = tid & 63, wid = tid >> 6;
  const int wm = wid >> 1, wn = wid & 1;

  const int srow = tid >> 3;
  const int scol = ((tid & 7) * 16) ^ ((srow & 7) << 4);
  const char* Ac = (const char*)hs;
  const char* Bc = (const char*)(w2t + (size_t)seg * DD * FF);
  const char* a[4]; const char* b[4];
#pragma unroll
  for (int r = 0; r < 4; ++r) {
    a[r] = Ac + (size_t)(hrow0 + tm * 128 + r * 32 + srow) * (FF * 2) + scol;
    b[r] = Bc + (size_t)(tn * 128 + r * 32 + srow) * (FF * 2) + scol;
  }

  f32x16 acc[2][2] = {};
  kloop32(FF / 64, a[0], a[1], a[2], a[3], b[0], b[1], b[2], b[3],
          As, Bs, tid, acc);

  const int l31 = lane & 31, lg = lane >> 5;
  const int rlim = rows - tm * 128;
  const float* b2 = (seg == 0) ? sb2 : rb2 + (size_t)(seg - 1) * DD;
  const int c0 = tn * 128 + wn * 64 + l31;
  const float bias0 = b2[c0], bias1 = b2[c0 + 32];
  float* ybase = yo + (size_t)(hrow0 + tm * 128) * DD;
#pragma unroll
  for (int mi = 0; mi < 2; ++mi)
#pragma unroll
    for (int reg = 0; reg < 16; ++reg) {
      int lr = wm * 64 + mi * 32 + (reg & 3) + 8 * (reg >> 2) + 4 * lg;
      if (lr < rlim) {
        float* orow = ybase + (size_t)lr * DD;
        orow[c0]      = acc[mi][0][reg] + bias0;
        orow[c0 + 32] = acc[mi][1][reg] + bias1;
      }
    }
}

// ---------------- combine: out[t] = yo[t] + w0*yo[T+s0] + w1*yo[T+s1] ----------------
__global__ void combine_kernel(const float* __restrict__ yo, const int* __restrict__ t2s,
                               const float* __restrict__ ew, float* __restrict__ out) {
  const int t = blockIdx.x, d = threadIdx.x;   // 256 threads x 4 floats
  const float4 a  = ((const float4*)(yo + (size_t)t * DD))[d];
  const int s0 = t2s[2*t], s1 = t2s[2*t+1];
  const float w0 = ew[2*t], w1 = ew[2*t+1];
  const float4 r0 = ((const float4*)(yo + (size_t)(TOK + s0) * DD))[d];
  const float4 r1 = ((const float4*)(yo + (size_t)(TOK + s1) * DD))[d];
  float4 r;
  r.x = a.x + w0 * r0.x + w1 * r1.x;
  r.y = a.y + w0 * r0.y + w1 * r1.y;
  r.z = a.z + w0 * r0.z + w1 * r1.z;
  r.w = a.w + w0 * r0.w + w1 * r1.w;
  ((float4*)(out + (size_t)t * DD))[d] = r;
}

// ---------------- launch ----------------
extern "C" void kernel_launch(void* const* d_in, const int* in_sizes, int n_in,
                              void* d_out, int out_size, void* d_ws, size_t ws_size,
                              hipStream_t stream) {
  const float* x   = (const float*)d_in[0];
  const float* gw  = (const float*)d_in[1];
  const float* gb  = (const float*)d_in[2];
  const float* sw1 = (const float*)d_in[3];
  const float* sb1 = (const float*)d_in[4];
  const float* sw2 = (const float*)d_in[5];
  const float* sb2 = (const float*)d_in[6];
  const float* rw1 = (const float*)d_in[7];
  const float* rb1 = (const float*)d_in[8];
  const float* rw2 = (const float*)d_in[9];
  const float* rb2 = (const float*)d_in[10];
  float* out = (float*)d_out;

  char* p = (char*)d_ws;
  auto alloc = [&](size_t bytes) { char* r = p; p += (bytes + 255) & ~(size_t)255; return r; };
  int*   counts = (int*)alloc(EE * 4);
  int*   eidx   = (int*)alloc((size_t)2 * TOK * 4);
  int*   epos   = (int*)alloc((size_t)2 * TOK * 4);
  float* ew     = (float*)alloc((size_t)2 * TOK * 4);
  int*   s2t    = (int*)alloc((size_t)PADT * 4);
  float* swt    = (float*)alloc((size_t)PADT * 4);
  int*   t2s    = (int*)alloc((size_t)2 * TOK * 4);
  u16*   xb     = (u16*)alloc((size_t)TOK * DD * 2);
  u16*   w1t    = (u16*)alloc((size_t)9 * TWOF * DD * 2);
  u16*   w2t    = (u16*)alloc((size_t)9 * DD * FF * 2);
  u16*   hs     = (u16*)alloc((size_t)(TOK + PADT + 128) * FF * 2);
  // yo aliases w1t: gemm2 runs strictly after gemm1 (same stream); ~105MB <= 151MB
  float* yo     = (float*)w1t;

  hipMemsetAsync(counts, 0, EE * 4, stream);
  hipMemsetAsync(s2t, 0, (size_t)PADT * 4, stream);
  gate_kernel<<<TOK / 4, 256, 0, stream>>>(x, gw, gb, counts, eidx, epos, ew, xb);
  slot_kernel<<<(2 * TOK) / 256, 256, 0, stream>>>(eidx, epos, ew, counts, s2t, swt, t2s);
  wt_kernel<<<dim3(TWOF / 64, DD / 64, 9), 256, 0, stream>>>(sw1, rw1, w1t, DD, TWOF, 1);
  wt_kernel<<<dim3(DD / 64, FF / 64, 9), 256, 0, stream>>>(sw2, rw2, w2t, FF, DD, 0);
  gemm1_kernel<<<dim3(64, 200), 256, 0, stream>>>(xb, s2t, w1t, sb1, rb1, counts, hs);
  gemm2_kernel<<<dim3(8, 200), 256, 0, stream>>>(hs, w2t, sb2, rb2, counts, yo);
  combine_kernel<<<TOK, 256, 0, stream>>>(yo, t2s, ew, out);
}

// Round 11
// 1091.219 us; speedup vs baseline: 9.6052x; 1.1262x over previous
//
#include <hip/hip_runtime.h>

#define TOK   8192
#define DD    1024
#define FF    4096
#define EE    8
#define TWOF  8192
#define NSLOT 16384   // TOK * top_k(2)
#define PADT  17408   // NSLOT + 8*128 (per-expert 128-row padding bound)

typedef unsigned short u16;
typedef float  f32x16 __attribute__((ext_vector_type(16)));
typedef __bf16 bf16x8 __attribute__((ext_vector_type(8)));

__device__ __forceinline__ u16 f2b(float f) {
  unsigned u = __builtin_bit_cast(unsigned, f);
  u += 0x7fffu + ((u >> 16) & 1u);   // RNE; inputs finite
  return (u16)(u >> 16);
}

__device__ __forceinline__ void ldslds16(const void* g, void* l) {
  __builtin_amdgcn_global_load_lds((const __attribute__((address_space(1))) void*)g,
                                   (__attribute__((address_space(3))) void*)l, 16, 0, 0);
}

// ---------------- gate (+x->bf16 convert fused): logits, softmax, top-2 ----------------
__global__ void gate_kernel(const float* __restrict__ x, const float* __restrict__ gw,
                            const float* __restrict__ gb, int* __restrict__ counts,
                            int* __restrict__ eidx, int* __restrict__ epos,
                            float* __restrict__ ew, u16* __restrict__ xb) {
  const int wave = threadIdx.x >> 6, lane = threadIdx.x & 63;
  const int t = blockIdx.x * 4 + wave;
  float acc[EE] = {0,0,0,0,0,0,0,0};
  const float* xr = x + (size_t)t * DD;
  u16* xbr = xb + (size_t)t * DD;
#pragma unroll
  for (int i = 0; i < DD / 256; ++i) {              // 4 float4-iters
    const int f = i * 64 + lane;                    // float4 index
    const float4 v = ((const float4*)xr)[f];
    const int d = f * 4;
    const float* g = gw + (size_t)d * EE;
#pragma unroll
    for (int e = 0; e < EE; ++e)
      acc[e] += v.x * g[e] + v.y * g[EE + e] + v.z * g[2 * EE + e] + v.w * g[3 * EE + e];
    uint2 pk;
    pk.x = (unsigned)f2b(v.x) | ((unsigned)f2b(v.y) << 16);
    pk.y = (unsigned)f2b(v.z) | ((unsigned)f2b(v.w) << 16);
    ((uint2*)xbr)[f] = pk;
  }
#pragma unroll
  for (int e = 0; e < EE; ++e)
#pragma unroll
    for (int off = 32; off > 0; off >>= 1) acc[e] += __shfl_down(acc[e], off);
  if (lane == 0) {
    float l[EE];
#pragma unroll
    for (int e = 0; e < EE; ++e) l[e] = acc[e] + gb[e];
    int i0 = 0;
    for (int e = 1; e < EE; ++e) if (l[e] > l[i0]) i0 = e;
    int i1 = (i0 == 0) ? 1 : 0;
    for (int e = 0; e < EE; ++e) { if (e == i0) continue; if (l[e] > l[i1]) i1 = e; }
    float m = l[0];
    for (int e = 1; e < EE; ++e) m = fmaxf(m, l[e]);
    float s = 0.f, p[EE];
    for (int e = 0; e < EE; ++e) { p[e] = __expf(l[e] - m); s += p[e]; }
    float w0 = p[i0] / s, w1 = p[i1] / s;
    int p0 = atomicAdd(&counts[i0], 1);
    int p1 = atomicAdd(&counts[i1], 1);
    eidx[2*t] = i0; eidx[2*t+1] = i1;
    epos[2*t] = p0; epos[2*t+1] = p1;
    ew[2*t] = w0;  ew[2*t+1] = w1;
  }
}

// slot: inline 128-aligned prefix over counts (8 ints, L2-hot)
__global__ void slot_kernel(const int* __restrict__ eidx, const int* __restrict__ epos,
                            const float* __restrict__ ew, const int* __restrict__ counts,
                            int* __restrict__ s2t, float* __restrict__ swt,
                            int* __restrict__ t2s) {
  int i = blockIdx.x * 256 + threadIdx.x;           // 0..2T-1
  int e = eidx[i];
  int off = 0;
  for (int j = 0; j < e; ++j) off += (counts[j] + 127) & ~127;
  int slot = off + epos[i];
  s2t[slot] = i >> 1;
  swt[slot] = ew[i];
  t2s[i] = slot;
}

// transpose-convert weights: dst[seg][n][k] (bf16) = src[seg][k][oc(n)] (f32)
// 64k x 64n tile; float4 reads (contiguous within 32-col permute groups),
// 128B-coalesced uint4 writes (8 lanes cover one output row's 64 k).
// permute (w1 only): interleave a/b halves in 32-col groups (SwiGLU pairing)
__global__ void wt_kernel(const float* __restrict__ srcS, const float* __restrict__ srcR,
                          u16* __restrict__ dst, int K, int N, int permute) {
  __shared__ float tile[64][65];
  const int seg = blockIdx.z;
  const float* src = (seg == 0) ? srcS : srcR + (size_t)(seg - 1) * K * N;
  const int pc0 = blockIdx.x * 64, k0 = blockIdx.y * 64;
  const int tid = threadIdx.x;
  {
    const int kk = tid >> 2;
    const float* srow = src + (size_t)(k0 + kk) * N;
#pragma unroll
    for (int c4 = 0; c4 < 4; ++c4) {
      const int j = (tid & 3) * 4 + c4 * 16;        // j%32 <= 28: float4-safe
      const int n = pc0 + j;
      const int oc = permute ? (((n >> 6) << 5) + (n & 31) + ((n & 32) ? FF : 0)) : n;
      const float4 v = *(const float4*)(srow + oc);
      tile[kk][j]     = v.x; tile[kk][j + 1] = v.y;
      tile[kk][j + 2] = v.z; tile[kk][j + 3] = v.w;
    }
  }
  __syncthreads();
  {
    const int c = tid & 7;                          // k-chunk (8 u16)
#pragma unroll
    for (int p = 0; p < 2; ++p) {
      const int pp = p * 32 + (tid >> 3);           // output row (n)
      u16* drow = dst + (size_t)seg * N * K + (size_t)(pc0 + pp) * K + k0;
      uint4 v; unsigned* pv = (unsigned*)&v;
#pragma unroll
      for (int q = 0; q < 4; ++q)
        pv[q] = (unsigned)f2b(tile[c * 8 + 2 * q][pp]) |
                ((unsigned)f2b(tile[c * 8 + 2 * q + 1][pp]) << 16);
      *(uint4*)(drow + c * 8) = v;                  // 8 lanes -> 128B contiguous
    }
  }
}

// ================= 128x128x64 GEMM core — 32x32x16 MFMA (R6-proven) =================
// 4 waves (2Mx2N), per-wave 64x64 (2x2 frags of 32x32). LDS 32 KiB -> ~4 blocks/CU.
// Swizzle byte col ^= (row&7)<<4 both sides (gload source + ds_read).

__device__ __forceinline__ void kloop32(int niter,
    const char* a0, const char* a1, const char* a2, const char* a3,
    const char* b0, const char* b1, const char* b2, const char* b3,
    u16* As, u16* Bs, int tid, f32x16 (&acc)[2][2]) {
  const int lane = tid & 63, l31 = lane & 31, kg = (lane >> 5) * 16;
  const int wid = tid >> 6, wm = wid >> 1, wn = wid & 1;
  const int C = (l31 & 7) << 4;
  const char* rA[4]; const char* rB[4];
#pragma unroll
  for (int ks = 0; ks < 4; ++ks) {        // 4 k-windows of 16 within BK=64
    const int o = (ks * 32 + kg) ^ C;
    rA[ks] = (const char*)As + (wm * 64 + l31) * 128 + o;
    rB[ks] = (const char*)Bs + (wn * 64 + l31) * 128 + o;
  }
  for (int it = 0; it < niter; ++it) {
    const long long kb = (long long)it * 128;        // 64 u16 per iter
    ldslds16(a0 + kb, As + tid * 8);
    ldslds16(a1 + kb, As + 2048 + tid * 8);
    ldslds16(a2 + kb, As + 4096 + tid * 8);
    ldslds16(a3 + kb, As + 6144 + tid * 8);
    ldslds16(b0 + kb, Bs + tid * 8);
    ldslds16(b1 + kb, Bs + 2048 + tid * 8);
    ldslds16(b2 + kb, Bs + 4096 + tid * 8);
    ldslds16(b3 + kb, Bs + 6144 + tid * 8);
    __syncthreads();
#pragma unroll
    for (int ks = 0; ks < 4; ++ks) {
      bf16x8 af0 = *(const bf16x8*)(rA[ks]);
      bf16x8 af1 = *(const bf16x8*)(rA[ks] + 4096);   // +32 rows
      bf16x8 bq0 = *(const bf16x8*)(rB[ks]);
      bf16x8 bq1 = *(const bf16x8*)(rB[ks] + 4096);
      acc[0][0] = __builtin_amdgcn_mfma_f32_32x32x16_bf16(af0, bq0, acc[0][0], 0, 0, 0);
      acc[0][1] = __builtin_amdgcn_mfma_f32_32x32x16_bf16(af0, bq1, acc[0][1], 0, 0, 0);
      acc[1][0] = __builtin_amdgcn_mfma_f32_32x32x16_bf16(af1, bq0, acc[1][0], 0, 0, 0);
      acc[1][1] = __builtin_amdgcn_mfma_f32_32x32x16_bf16(af1, bq1, acc[1][1], 0, 0, 0);
    }
    __syncthreads();
  }
}

// map compact g -> (seg, tm, rowstart, rows) scanning counts (no meta buffer)
__device__ __forceinline__ bool seg_map(int g, const int* __restrict__ counts,
                                        int& seg, int& tm, int& rowstart, int& rows) {
  if (g < 64) { seg = 0; tm = g; rowstart = 0; rows = TOK; return true; }
  int gr = g - 64, off = 0;
  for (int e = 0; e < EE; ++e) {
    int c = counts[e];
    int nb = (c + 127) >> 7;
    if (gr < nb) { seg = e + 1; tm = gr; rowstart = off; rows = c; return true; }
    gr -= nb;
    off += (c + 127) & ~127;
  }
  return false;
}

// ---------------- GEMM1: x @ w1t(permuted) -> SwiGLU -> hs bf16 ----------------
__global__ __launch_bounds__(256, 4)
void gemm1_kernel(const u16* __restrict__ xb, const int* __restrict__ s2t,
                  const u16* __restrict__ w1t, const float* __restrict__ sb1,
                  const float* __restrict__ rb1, const int* __restrict__ counts,
                  u16* __restrict__ hs) {
  __shared__ __align__(16) u16 As[128 * 64];
  __shared__ __align__(16) u16 Bs[128 * 64];
  // XCD L2 chunking: same tn -> same lin&7 -> same XCD; B-panel per XCD = 2 MB (L2-fit)
  const int lin = blockIdx.x + 64 * blockIdx.y;
  const int tn = (lin & 7) * 8 + ((lin >> 3) & 7);
  const int g = lin >> 6;
  int seg, tm, rowstart, rows;
  if (!seg_map(g, counts, seg, tm, rowstart, rows)) return;
  const int hsbase = (seg == 0) ? 0 : TOK + rowstart;
  const int tid = threadIdx.x, lane = tid & 63, wid = tid >> 6;
  const int wm = wid >> 1, wn = wid & 1;

  const int srow = tid >> 3;
  const int scol = ((tid & 7) * 16) ^ ((srow & 7) << 4);
  const char* Ac = (const char*)xb;
  const char* Bc = (const char*)(w1t + (size_t)seg * TWOF * DD);
  const char* a[4]; const char* b[4];
#pragma unroll
  for (int r = 0; r < 4; ++r) {
    int rbase = tm * 128 + r * 32 + srow;
    int rg = (seg == 0) ? rbase : s2t[rowstart + rbase];   // pad slots -> token 0
    a[r] = Ac + (size_t)rg * (DD * 2) + scol;
    b[r] = Bc + (size_t)(tn * 128 + r * 32 + srow) * (DD * 2) + scol;
  }

  f32x16 acc[2][2] = {};
  kloop32(DD / 64, a[0], a[1], a[2], a[3], b[0], b[1], b[2], b[3],
          As, Bs, tid, acc);

  const int l31 = lane & 31, lg = lane >> 5;
  const int rlim = rows - tm * 128;
  const float* b1 = (seg == 0) ? sb1 : rb1 + (size_t)(seg - 1) * TWOF;
  const int f = (tn * 2 + wn) * 32 + l31;
  const float ba = b1[f], bb = b1[FF + f];
  u16* hbase = hs + (size_t)(hsbase + tm * 128) * FF;
#pragma unroll
  for (int mi = 0; mi < 2; ++mi)
#pragma unroll
    for (int reg = 0; reg < 16; ++reg) {
      int lr = wm * 64 + mi * 32 + (reg & 3) + 8 * (reg >> 2) + 4 * lg;
      if (lr < rlim) {
        float av = acc[mi][0][reg] + ba;
        float bv = acc[mi][1][reg] + bb;
        float sv = av / (1.0f + __expf(-av)) * bv;
        hbase[(size_t)lr * FF + f] = f2b(sv);
      }
    }
}

// ---------------- GEMM2: hs @ w2t -> yo (f32, all segments, no atomics) ----------------
__global__ __launch_bounds__(256, 4)
void gemm2_kernel(const u16* __restrict__ hs, const u16* __restrict__ w2t,
                  const float* __restrict__ sb2, const float* __restrict__ rb2,
                  const int* __restrict__ counts, float* __restrict__ yo) {
  __shared__ __align__(16) u16 As[128 * 64];
  __shared__ __align__(16) u16 Bs[128 * 64];
  const int tn = blockIdx.x;                         // 8 tn -> block lin%8 -> XCD-affine
  const int g = blockIdx.y;
  int seg, tm, rowstart, rows;
  if (!seg_map(g, counts, seg, tm, rowstart, rows)) return;
  const int hrow0 = (seg == 0) ? 0 : TOK + rowstart;
  const int tid = threadIdx.x, lane = tid & 63, wid = tid >> 6;
  const int wm = wid >> 1, wn = wid & 1;

  const int srow = tid >> 3;
  const int scol = ((tid & 7) * 16) ^ ((srow & 7) << 4);
  const char* Ac = (const char*)hs;
  const char* Bc = (const char*)(w2t + (size_t)seg * DD * FF);
  const char* a[4]; const char* b[4];
#pragma unroll
  for (int r = 0; r < 4; ++r) {
    a[r] = Ac + (size_t)(hrow0 + tm * 128 + r * 32 + srow) * (FF * 2) + scol;
    b[r] = Bc + (size_t)(tn * 128 + r * 32 + srow) * (FF * 2) + scol;
  }

  f32x16 acc[2][2] = {};
  kloop32(FF / 64, a[0], a[1], a[2], a[3], b[0], b[1], b[2], b[3],
          As, Bs, tid, acc);

  const int l31 = lane & 31, lg = lane >> 5;
  const int rlim = rows - tm * 128;
  const float* b2 = (seg == 0) ? sb2 : rb2 + (size_t)(seg - 1) * DD;
  const int c0 = tn * 128 + wn * 64 + l31;
  const float bias0 = b2[c0], bias1 = b2[c0 + 32];
  float* ybase = yo + (size_t)(hrow0 + tm * 128) * DD;
#pragma unroll
  for (int mi = 0; mi < 2; ++mi)
#pragma unroll
    for (int reg = 0; reg < 16; ++reg) {
      int lr = wm * 64 + mi * 32 + (reg & 3) + 8 * (reg >> 2) + 4 * lg;
      if (lr < rlim) {
        float* orow = ybase + (size_t)lr * DD;
        orow[c0]      = acc[mi][0][reg] + bias0;
        orow[c0 + 32] = acc[mi][1][reg] + bias1;
      }
    }
}

// ---------------- combine: out[t] = yo[t] + w0*yo[T+s0] + w1*yo[T+s1] ----------------
__global__ void combine_kernel(const float* __restrict__ yo, const int* __restrict__ t2s,
                               const float* __restrict__ ew, float* __restrict__ out) {
  const int t = blockIdx.x, d = threadIdx.x;   // 256 threads x 4 floats
  const float4 a  = ((const float4*)(yo + (size_t)t * DD))[d];
  const int s0 = t2s[2*t], s1 = t2s[2*t+1];
  const float w0 = ew[2*t], w1 = ew[2*t+1];
  const float4 r0 = ((const float4*)(yo + (size_t)(TOK + s0) * DD))[d];
  const float4 r1 = ((const float4*)(yo + (size_t)(TOK + s1) * DD))[d];
  float4 r;
  r.x = a.x + w0 * r0.x + w1 * r1.x;
  r.y = a.y + w0 * r0.y + w1 * r1.y;
  r.z = a.z + w0 * r0.z + w1 * r1.z;
  r.w = a.w + w0 * r0.w + w1 * r1.w;
  ((float4*)(out + (size_t)t * DD))[d] = r;
}

// ---------------- launch ----------------
extern "C" void kernel_launch(void* const* d_in, const int* in_sizes, int n_in,
                              void* d_out, int out_size, void* d_ws, size_t ws_size,
                              hipStream_t stream) {
  const float* x   = (const float*)d_in[0];
  const float* gw  = (const float*)d_in[1];
  const float* gb  = (const float*)d_in[2];
  const float* sw1 = (const float*)d_in[3];
  const float* sb1 = (const float*)d_in[4];
  const float* sw2 = (const float*)d_in[5];
  const float* sb2 = (const float*)d_in[6];
  const float* rw1 = (const float*)d_in[7];
  const float* rb1 = (const float*)d_in[8];
  const float* rw2 = (const float*)d_in[9];
  const float* rb2 = (const float*)d_in[10];
  float* out = (float*)d_out;

  char* p = (char*)d_ws;
  auto alloc = [&](size_t bytes) { char* r = p; p += (bytes + 255) & ~(size_t)255; return r; };
  int*   counts = (int*)alloc(EE * 4);
  int*   eidx   = (int*)alloc((size_t)2 * TOK * 4);
  int*   epos   = (int*)alloc((size_t)2 * TOK * 4);
  float* ew     = (float*)alloc((size_t)2 * TOK * 4);
  int*   s2t    = (int*)alloc((size_t)PADT * 4);
  float* swt    = (float*)alloc((size_t)PADT * 4);
  int*   t2s    = (int*)alloc((size_t)2 * TOK * 4);
  u16*   xb     = (u16*)alloc((size_t)TOK * DD * 2);
  u16*   w1t    = (u16*)alloc((size_t)9 * TWOF * DD * 2);
  u16*   w2t    = (u16*)alloc((size_t)9 * DD * FF * 2);
  u16*   hs     = (u16*)alloc((size_t)(TOK + PADT + 128) * FF * 2);
  // yo aliases w1t: gemm2 runs strictly after gemm1 (same stream); ~105MB <= 151MB
  float* yo     = (float*)w1t;

  hipMemsetAsync(counts, 0, EE * 4, stream);
  hipMemsetAsync(s2t, 0, (size_t)PADT * 4, stream);
  gate_kernel<<<TOK / 4, 256, 0, stream>>>(x, gw, gb, counts, eidx, epos, ew, xb);
  slot_kernel<<<(2 * TOK) / 256, 256, 0, stream>>>(eidx, epos, ew, counts, s2t, swt, t2s);
  wt_kernel<<<dim3(TWOF / 64, DD / 64, 9), 256, 0, stream>>>(sw1, rw1, w1t, DD, TWOF, 1);
  wt_kernel<<<dim3(DD / 64, FF / 64, 9), 256, 0, stream>>>(sw2, rw2, w2t, FF, DD, 0);
  gemm1_kernel<<<dim3(64, 200), 256, 0, stream>>>(xb, s2t, w1t, sb1, rb1, counts, hs);
  gemm2_kernel<<<dim3(8, 200), 256, 0, stream>>>(hs, w2t, sb2, rb2, counts, yo);
  combine_kernel<<<TOK, 256, 0, stream>>>(yo, t2s, ew, out);
}

// Round 12
// 1078.845 us; speedup vs baseline: 9.7154x; 1.0115x over previous
//
#include <hip/hip_runtime.h>

#define TOK   8192
#define DD    1024
#define FF    4096
#define EE    8
#define TWOF  8192
#define NSLOT 16384   // TOK * top_k(2)
#define PADT  17408   // NSLOT + 8*128 (per-expert 128-row padding bound)

typedef unsigned short u16;
typedef float  f32x16 __attribute__((ext_vector_type(16)));
typedef __bf16 bf16x8 __attribute__((ext_vector_type(8)));

__device__ __forceinline__ u16 f2b(float f) {
  unsigned u = __builtin_bit_cast(unsigned, f);
  u += 0x7fffu + ((u >> 16) & 1u);   // RNE; inputs finite
  return (u16)(u >> 16);
}

__device__ __forceinline__ float b2f(u16 b) {
  return __builtin_bit_cast(float, (unsigned)b << 16);
}

__device__ __forceinline__ void ldslds16(const void* g, void* l) {
  __builtin_amdgcn_global_load_lds((const __attribute__((address_space(1))) void*)g,
                                   (__attribute__((address_space(3))) void*)l, 16, 0, 0);
}

// ---------------- gate (+x->bf16 convert fused): logits, softmax, top-2 ----------------
__global__ void gate_kernel(const float* __restrict__ x, const float* __restrict__ gw,
                            const float* __restrict__ gb, int* __restrict__ counts,
                            int* __restrict__ eidx, int* __restrict__ epos,
                            float* __restrict__ ew, u16* __restrict__ xb) {
  const int wave = threadIdx.x >> 6, lane = threadIdx.x & 63;
  const int t = blockIdx.x * 4 + wave;
  float acc[EE] = {0,0,0,0,0,0,0,0};
  const float* xr = x + (size_t)t * DD;
  u16* xbr = xb + (size_t)t * DD;
#pragma unroll
  for (int i = 0; i < DD / 256; ++i) {              // 4 float4-iters
    const int f = i * 64 + lane;                    // float4 index
    const float4 v = ((const float4*)xr)[f];
    const int d = f * 4;
    const float* g = gw + (size_t)d * EE;
#pragma unroll
    for (int e = 0; e < EE; ++e)
      acc[e] += v.x * g[e] + v.y * g[EE + e] + v.z * g[2 * EE + e] + v.w * g[3 * EE + e];
    uint2 pk;
    pk.x = (unsigned)f2b(v.x) | ((unsigned)f2b(v.y) << 16);
    pk.y = (unsigned)f2b(v.z) | ((unsigned)f2b(v.w) << 16);
    ((uint2*)xbr)[f] = pk;
  }
#pragma unroll
  for (int e = 0; e < EE; ++e)
#pragma unroll
    for (int off = 32; off > 0; off >>= 1) acc[e] += __shfl_down(acc[e], off);
  if (lane == 0) {
    float l[EE];
#pragma unroll
    for (int e = 0; e < EE; ++e) l[e] = acc[e] + gb[e];
    int i0 = 0;
    for (int e = 1; e < EE; ++e) if (l[e] > l[i0]) i0 = e;
    int i1 = (i0 == 0) ? 1 : 0;
    for (int e = 0; e < EE; ++e) { if (e == i0) continue; if (l[e] > l[i1]) i1 = e; }
    float m = l[0];
    for (int e = 1; e < EE; ++e) m = fmaxf(m, l[e]);
    float s = 0.f, p[EE];
    for (int e = 0; e < EE; ++e) { p[e] = __expf(l[e] - m); s += p[e]; }
    float w0 = p[i0] / s, w1 = p[i1] / s;
    int p0 = atomicAdd(&counts[i0], 1);
    int p1 = atomicAdd(&counts[i1], 1);
    eidx[2*t] = i0; eidx[2*t+1] = i1;
    epos[2*t] = p0; epos[2*t+1] = p1;
    ew[2*t] = w0;  ew[2*t+1] = w1;
  }
}

// slot: inline 128-aligned prefix over counts (8 ints, L2-hot)
__global__ void slot_kernel(const int* __restrict__ eidx, const int* __restrict__ epos,
                            const float* __restrict__ ew, const int* __restrict__ counts,
                            int* __restrict__ s2t, float* __restrict__ swt,
                            int* __restrict__ t2s) {
  int i = blockIdx.x * 256 + threadIdx.x;           // 0..2T-1
  int e = eidx[i];
  int off = 0;
  for (int j = 0; j < e; ++j) off += (counts[j] + 127) & ~127;
  int slot = off + epos[i];
  s2t[slot] = i >> 1;
  swt[slot] = ew[i];
  t2s[i] = slot;
}

// transpose-convert weights: dst[seg][n][k] (bf16) = src[seg][k][oc(n)] (f32)
// 64k x 64n tile; float4 reads (contiguous within 32-col permute groups),
// 128B-coalesced uint4 writes (8 lanes cover one output row's 64 k).
// permute (w1 only): interleave a/b halves in 32-col groups (SwiGLU pairing)
__global__ void wt_kernel(const float* __restrict__ srcS, const float* __restrict__ srcR,
                          u16* __restrict__ dst, int K, int N, int permute) {
  __shared__ float tile[64][65];
  const int seg = blockIdx.z;
  const float* src = (seg == 0) ? srcS : srcR + (size_t)(seg - 1) * K * N;
  const int pc0 = blockIdx.x * 64, k0 = blockIdx.y * 64;
  const int tid = threadIdx.x;
  {
    const int kk = tid >> 2;
    const float* srow = src + (size_t)(k0 + kk) * N;
#pragma unroll
    for (int c4 = 0; c4 < 4; ++c4) {
      const int j = (tid & 3) * 4 + c4 * 16;        // j%32 <= 28: float4-safe
      const int n = pc0 + j;
      const int oc = permute ? (((n >> 6) << 5) + (n & 31) + ((n & 32) ? FF : 0)) : n;
      const float4 v = *(const float4*)(srow + oc);
      tile[kk][j]     = v.x; tile[kk][j + 1] = v.y;
      tile[kk][j + 2] = v.z; tile[kk][j + 3] = v.w;
    }
  }
  __syncthreads();
  {
    const int c = tid & 7;                          // k-chunk (8 u16)
#pragma unroll
    for (int p = 0; p < 2; ++p) {
      const int pp = p * 32 + (tid >> 3);           // output row (n)
      u16* drow = dst + (size_t)seg * N * K + (size_t)(pc0 + pp) * K + k0;
      uint4 v; unsigned* pv = (unsigned*)&v;
#pragma unroll
      for (int q = 0; q < 4; ++q)
        pv[q] = (unsigned)f2b(tile[c * 8 + 2 * q][pp]) |
                ((unsigned)f2b(tile[c * 8 + 2 * q + 1][pp]) << 16);
      *(uint4*)(drow + c * 8) = v;                  // 8 lanes -> 128B contiguous
    }
  }
}

// ================= 128x128x64 GEMM core — 32x32x16 MFMA (R6-proven) =================
// 4 waves (2Mx2N), per-wave 64x64 (2x2 frags of 32x32). LDS 32 KiB -> ~4 blocks/CU.
// Swizzle byte col ^= (row&7)<<4 both sides (gload source + ds_read).

__device__ __forceinline__ void kloop32(int niter,
    const char* a0, const char* a1, const char* a2, const char* a3,
    const char* b0, const char* b1, const char* b2, const char* b3,
    u16* As, u16* Bs, int tid, f32x16 (&acc)[2][2]) {
  const int lane = tid & 63, l31 = lane & 31, kg = (lane >> 5) * 16;
  const int wid = tid >> 6, wm = wid >> 1, wn = wid & 1;
  const int C = (l31 & 7) << 4;
  const char* rA[4]; const char* rB[4];
#pragma unroll
  for (int ks = 0; ks < 4; ++ks) {        // 4 k-windows of 16 within BK=64
    const int o = (ks * 32 + kg) ^ C;
    rA[ks] = (const char*)As + (wm * 64 + l31) * 128 + o;
    rB[ks] = (const char*)Bs + (wn * 64 + l31) * 128 + o;
  }
  for (int it = 0; it < niter; ++it) {
    const long long kb = (long long)it * 128;        // 64 u16 per iter
    ldslds16(a0 + kb, As + tid * 8);
    ldslds16(a1 + kb, As + 2048 + tid * 8);
    ldslds16(a2 + kb, As + 4096 + tid * 8);
    ldslds16(a3 + kb, As + 6144 + tid * 8);
    ldslds16(b0 + kb, Bs + tid * 8);
    ldslds16(b1 + kb, Bs + 2048 + tid * 8);
    ldslds16(b2 + kb, Bs + 4096 + tid * 8);
    ldslds16(b3 + kb, Bs + 6144 + tid * 8);
    __syncthreads();
#pragma unroll
    for (int ks = 0; ks < 4; ++ks) {
      bf16x8 af0 = *(const bf16x8*)(rA[ks]);
      bf16x8 af1 = *(const bf16x8*)(rA[ks] + 4096);   // +32 rows
      bf16x8 bq0 = *(const bf16x8*)(rB[ks]);
      bf16x8 bq1 = *(const bf16x8*)(rB[ks] + 4096);
      acc[0][0] = __builtin_amdgcn_mfma_f32_32x32x16_bf16(af0, bq0, acc[0][0], 0, 0, 0);
      acc[0][1] = __builtin_amdgcn_mfma_f32_32x32x16_bf16(af0, bq1, acc[0][1], 0, 0, 0);
      acc[1][0] = __builtin_amdgcn_mfma_f32_32x32x16_bf16(af1, bq0, acc[1][0], 0, 0, 0);
      acc[1][1] = __builtin_amdgcn_mfma_f32_32x32x16_bf16(af1, bq1, acc[1][1], 0, 0, 0);
    }
    __syncthreads();
  }
}

// map compact g -> (seg, tm, rowstart, rows) scanning counts (no meta buffer)
__device__ __forceinline__ bool seg_map(int g, const int* __restrict__ counts,
                                        int& seg, int& tm, int& rowstart, int& rows) {
  if (g < 64) { seg = 0; tm = g; rowstart = 0; rows = TOK; return true; }
  int gr = g - 64, off = 0;
  for (int e = 0; e < EE; ++e) {
    int c = counts[e];
    int nb = (c + 127) >> 7;
    if (gr < nb) { seg = e + 1; tm = gr; rowstart = off; rows = c; return true; }
    gr -= nb;
    off += (c + 127) & ~127;
  }
  return false;
}

// ---------------- GEMM1: x @ w1t(permuted) -> SwiGLU -> hs bf16 ----------------
__global__ __launch_bounds__(256, 4)
void gemm1_kernel(const u16* __restrict__ xb, const int* __restrict__ s2t,
                  const u16* __restrict__ w1t, const float* __restrict__ sb1,
                  const float* __restrict__ rb1, const int* __restrict__ counts,
                  u16* __restrict__ hs) {
  __shared__ __align__(16) u16 As[128 * 64];
  __shared__ __align__(16) u16 Bs[128 * 64];
  // XCD L2 chunking: same tn -> same lin&7 -> same XCD; B-panel per XCD = 2 MB (L2-fit)
  const int lin = blockIdx.x + 64 * blockIdx.y;
  const int tn = (lin & 7) * 8 + ((lin >> 3) & 7);
  const int g = lin >> 6;
  int seg, tm, rowstart, rows;
  if (!seg_map(g, counts, seg, tm, rowstart, rows)) return;
  const int hsbase = (seg == 0) ? 0 : TOK + rowstart;
  const int tid = threadIdx.x, lane = tid & 63, wid = tid >> 6;
  const int wm = wid >> 1, wn = wid & 1;

  const int srow = tid >> 3;
  const int scol = ((tid & 7) * 16) ^ ((srow & 7) << 4);
  const char* Ac = (const char*)xb;
  const char* Bc = (const char*)(w1t + (size_t)seg * TWOF * DD);
  const char* a[4]; const char* b[4];
#pragma unroll
  for (int r = 0; r < 4; ++r) {
    int rbase = tm * 128 + r * 32 + srow;
    int rg = (seg == 0) ? rbase : s2t[rowstart + rbase];   // pad slots -> token 0
    a[r] = Ac + (size_t)rg * (DD * 2) + scol;
    b[r] = Bc + (size_t)(tn * 128 + r * 32 + srow) * (DD * 2) + scol;
  }

  f32x16 acc[2][2] = {};
  kloop32(DD / 64, a[0], a[1], a[2], a[3], b[0], b[1], b[2], b[3],
          As, Bs, tid, acc);

  const int l31 = lane & 31, lg = lane >> 5;
  const int rlim = rows - tm * 128;
  const float* b1 = (seg == 0) ? sb1 : rb1 + (size_t)(seg - 1) * TWOF;
  const int f = (tn * 2 + wn) * 32 + l31;
  const float ba = b1[f], bb = b1[FF + f];
  u16* hbase = hs + (size_t)(hsbase + tm * 128) * FF;
#pragma unroll
  for (int mi = 0; mi < 2; ++mi)
#pragma unroll
    for (int reg = 0; reg < 16; ++reg) {
      int lr = wm * 64 + mi * 32 + (reg & 3) + 8 * (reg >> 2) + 4 * lg;
      if (lr < rlim) {
        float av = acc[mi][0][reg] + ba;
        float bv = acc[mi][1][reg] + bb;
        float sv = av / (1.0f + __expf(-av)) * bv;
        hbase[(size_t)lr * FF + f] = f2b(sv);
      }
    }
}

// ---------------- GEMM2: hs @ w2t -> yo (bf16, all segments, no atomics) ----------------
__global__ __launch_bounds__(256, 4)
void gemm2_kernel(const u16* __restrict__ hs, const u16* __restrict__ w2t,
                  const float* __restrict__ sb2, const float* __restrict__ rb2,
                  const int* __restrict__ counts, u16* __restrict__ yo) {
  __shared__ __align__(16) u16 As[128 * 64];
  __shared__ __align__(16) u16 Bs[128 * 64];
  const int tn = blockIdx.x;                         // 8 tn -> block lin%8 -> XCD-affine
  const int g = blockIdx.y;
  int seg, tm, rowstart, rows;
  if (!seg_map(g, counts, seg, tm, rowstart, rows)) return;
  const int hrow0 = (seg == 0) ? 0 : TOK + rowstart;
  const int tid = threadIdx.x, lane = tid & 63, wid = tid >> 6;
  const int wm = wid >> 1, wn = wid & 1;

  const int srow = tid >> 3;
  const int scol = ((tid & 7) * 16) ^ ((srow & 7) << 4);
  const char* Ac = (const char*)hs;
  const char* Bc = (const char*)(w2t + (size_t)seg * DD * FF);
  const char* a[4]; const char* b[4];
#pragma unroll
  for (int r = 0; r < 4; ++r) {
    a[r] = Ac + (size_t)(hrow0 + tm * 128 + r * 32 + srow) * (FF * 2) + scol;
    b[r] = Bc + (size_t)(tn * 128 + r * 32 + srow) * (FF * 2) + scol;
  }

  f32x16 acc[2][2] = {};
  kloop32(FF / 64, a[0], a[1], a[2], a[3], b[0], b[1], b[2], b[3],
          As, Bs, tid, acc);

  const int l31 = lane & 31, lg = lane >> 5;
  const int rlim = rows - tm * 128;
  const float* b2 = (seg == 0) ? sb2 : rb2 + (size_t)(seg - 1) * DD;
  const int c0 = tn * 128 + wn * 64 + l31;
  const float bias0 = b2[c0], bias1 = b2[c0 + 32];
  u16* ybase = yo + (size_t)(hrow0 + tm * 128) * DD;
#pragma unroll
  for (int mi = 0; mi < 2; ++mi)
#pragma unroll
    for (int reg = 0; reg < 16; ++reg) {
      int lr = wm * 64 + mi * 32 + (reg & 3) + 8 * (reg >> 2) + 4 * lg;
      if (lr < rlim) {
        u16* orow = ybase + (size_t)lr * DD;
        orow[c0]      = f2b(acc[mi][0][reg] + bias0);
        orow[c0 + 32] = f2b(acc[mi][1][reg] + bias1);
      }
    }
}

// ---------------- combine: out[t] = yo[t] + w0*yo[T+s0] + w1*yo[T+s1] ----------------
__global__ void combine_kernel(const u16* __restrict__ yo, const int* __restrict__ t2s,
                               const float* __restrict__ ew, float* __restrict__ out) {
  const int t = blockIdx.x, d = threadIdx.x;   // 256 threads x 4 elements
  const int s0 = t2s[2*t], s1 = t2s[2*t+1];
  const float w0 = ew[2*t], w1 = ew[2*t+1];
  const uint2 pa = ((const uint2*)(yo + (size_t)t * DD))[d];
  const uint2 p0 = ((const uint2*)(yo + (size_t)(TOK + s0) * DD))[d];
  const uint2 p1 = ((const uint2*)(yo + (size_t)(TOK + s1) * DD))[d];
  float4 r;
  r.x = b2f((u16)pa.x)         + w0 * b2f((u16)p0.x)         + w1 * b2f((u16)p1.x);
  r.y = b2f((u16)(pa.x >> 16)) + w0 * b2f((u16)(p0.x >> 16)) + w1 * b2f((u16)(p1.x >> 16));
  r.z = b2f((u16)pa.y)         + w0 * b2f((u16)p0.y)         + w1 * b2f((u16)p1.y);
  r.w = b2f((u16)(pa.y >> 16)) + w0 * b2f((u16)(p0.y >> 16)) + w1 * b2f((u16)(p1.y >> 16));
  ((float4*)(out + (size_t)t * DD))[d] = r;
}

// ---------------- launch ----------------
extern "C" void kernel_launch(void* const* d_in, const int* in_sizes, int n_in,
                              void* d_out, int out_size, void* d_ws, size_t ws_size,
                              hipStream_t stream) {
  const float* x   = (const float*)d_in[0];
  const float* gw  = (const float*)d_in[1];
  const float* gb  = (const float*)d_in[2];
  const float* sw1 = (const float*)d_in[3];
  const float* sb1 = (const float*)d_in[4];
  const float* sw2 = (const float*)d_in[5];
  const float* sb2 = (const float*)d_in[6];
  const float* rw1 = (const float*)d_in[7];
  const float* rb1 = (const float*)d_in[8];
  const float* rw2 = (const float*)d_in[9];
  const float* rb2 = (const float*)d_in[10];
  float* out = (float*)d_out;

  char* p = (char*)d_ws;
  auto alloc = [&](size_t bytes) { char* r = p; p += (bytes + 255) & ~(size_t)255; return r; };
  int*   counts = (int*)alloc(EE * 4);
  int*   eidx   = (int*)alloc((size_t)2 * TOK * 4);
  int*   epos   = (int*)alloc((size_t)2 * TOK * 4);
  float* ew     = (float*)alloc((size_t)2 * TOK * 4);
  int*   s2t    = (int*)alloc((size_t)PADT * 4);
  float* swt    = (float*)alloc((size_t)PADT * 4);
  int*   t2s    = (int*)alloc((size_t)2 * TOK * 4);
  u16*   xb     = (u16*)alloc((size_t)TOK * DD * 2);
  u16*   w1t    = (u16*)alloc((size_t)9 * TWOF * DD * 2);
  u16*   w2t    = (u16*)alloc((size_t)9 * DD * FF * 2);
  u16*   hs     = (u16*)alloc((size_t)(TOK + PADT + 128) * FF * 2);
  // yo (bf16) aliases w1t: gemm2 runs strictly after gemm1 (same stream); ~51MB <= 151MB
  u16*   yo     = (u16*)w1t;

  hipMemsetAsync(counts, 0, EE * 4, stream);
  hipMemsetAsync(s2t, 0, (size_t)PADT * 4, stream);
  gate_kernel<<<TOK / 4, 256, 0, stream>>>(x, gw, gb, counts, eidx, epos, ew, xb);
  slot_kernel<<<(2 * TOK) / 256, 256, 0, stream>>>(eidx, epos, ew, counts, s2t, swt, t2s);
  wt_kernel<<<dim3(TWOF / 64, DD / 64, 9), 256, 0, stream>>>(sw1, rw1, w1t, DD, TWOF, 1);
  wt_kernel<<<dim3(DD / 64, FF / 64, 9), 256, 0, stream>>>(sw2, rw2, w2t, FF, DD, 0);
  gemm1_kernel<<<dim3(64, 200), 256, 0, stream>>>(xb, s2t, w1t, sb1, rb1, counts, hs);
  gemm2_kernel<<<dim3(8, 200), 256, 0, stream>>>(hs, w2t, sb2, rb2, counts, yo);
  combine_kernel<<<TOK, 256, 0, stream>>>(yo, t2s, ew, out);
}

// Round 13
// 1072.640 us; speedup vs baseline: 9.7716x; 1.0058x over previous
//
#include <hip/hip_runtime.h>

#define TOK   8192
#define DD    1024
#define FF    4096
#define EE    8
#define TWOF  8192
#define NSLOT 16384   // TOK * top_k(2)
#define PADT  17408   // NSLOT + 8*128 (per-expert 128-row padding bound)

typedef unsigned short u16;
typedef float  f32x4  __attribute__((ext_vector_type(4)));
typedef __bf16 bf16x8 __attribute__((ext_vector_type(8)));

__device__ __forceinline__ u16 f2b(float f) {
  unsigned u = __builtin_bit_cast(unsigned, f);
  u += 0x7fffu + ((u >> 16) & 1u);   // RNE; inputs finite
  return (u16)(u >> 16);
}

__device__ __forceinline__ float b2f(u16 b) {
  return __builtin_bit_cast(float, (unsigned)b << 16);
}

__device__ __forceinline__ void ldslds16(const void* g, void* l) {
  __builtin_amdgcn_global_load_lds((const __attribute__((address_space(1))) void*)g,
                                   (__attribute__((address_space(3))) void*)l, 16, 0, 0);
}

// ---------------- gate (+x->bf16 convert fused): logits, softmax, top-2 ----------------
__global__ void gate_kernel(const float* __restrict__ x, const float* __restrict__ gw,
                            const float* __restrict__ gb, int* __restrict__ counts,
                            int* __restrict__ eidx, int* __restrict__ epos,
                            float* __restrict__ ew, u16* __restrict__ xb) {
  const int wave = threadIdx.x >> 6, lane = threadIdx.x & 63;
  const int t = blockIdx.x * 4 + wave;
  float acc[EE] = {0,0,0,0,0,0,0,0};
  const float* xr = x + (size_t)t * DD;
  u16* xbr = xb + (size_t)t * DD;
#pragma unroll
  for (int i = 0; i < DD / 256; ++i) {              // 4 float4-iters
    const int f = i * 64 + lane;                    // float4 index
    const float4 v = ((const float4*)xr)[f];
    const int d = f * 4;
    const float* g = gw + (size_t)d * EE;
#pragma unroll
    for (int e = 0; e < EE; ++e)
      acc[e] += v.x * g[e] + v.y * g[EE + e] + v.z * g[2 * EE + e] + v.w * g[3 * EE + e];
    uint2 pk;
    pk.x = (unsigned)f2b(v.x) | ((unsigned)f2b(v.y) << 16);
    pk.y = (unsigned)f2b(v.z) | ((unsigned)f2b(v.w) << 16);
    ((uint2*)xbr)[f] = pk;
  }
#pragma unroll
  for (int e = 0; e < EE; ++e)
#pragma unroll
    for (int off = 32; off > 0; off >>= 1) acc[e] += __shfl_down(acc[e], off);
  if (lane == 0) {
    float l[EE];
#pragma unroll
    for (int e = 0; e < EE; ++e) l[e] = acc[e] + gb[e];
    int i0 = 0;
    for (int e = 1; e < EE; ++e) if (l[e] > l[i0]) i0 = e;
    int i1 = (i0 == 0) ? 1 : 0;
    for (int e = 0; e < EE; ++e) { if (e == i0) continue; if (l[e] > l[i1]) i1 = e; }
    float m = l[0];
    for (int e = 1; e < EE; ++e) m = fmaxf(m, l[e]);
    float s = 0.f, p[EE];
    for (int e = 0; e < EE; ++e) { p[e] = __expf(l[e] - m); s += p[e]; }
    float w0 = p[i0] / s, w1 = p[i1] / s;
    int p0 = atomicAdd(&counts[i0], 1);
    int p1 = atomicAdd(&counts[i1], 1);
    eidx[2*t] = i0; eidx[2*t+1] = i1;
    epos[2*t] = p0; epos[2*t+1] = p1;
    ew[2*t] = w0;  ew[2*t+1] = w1;
  }
}

// slot: inline 128-aligned prefix over counts (8 ints, L2-hot)
__global__ void slot_kernel(const int* __restrict__ eidx, const int* __restrict__ epos,
                            const float* __restrict__ ew, const int* __restrict__ counts,
                            int* __restrict__ s2t, float* __restrict__ swt,
                            int* __restrict__ t2s) {
  int i = blockIdx.x * 256 + threadIdx.x;           // 0..2T-1
  int e = eidx[i];
  int off = 0;
  for (int j = 0; j < e; ++j) off += (counts[j] + 127) & ~127;
  int slot = off + epos[i];
  s2t[slot] = i >> 1;
  swt[slot] = ew[i];
  t2s[i] = slot;
}

// transpose-convert weights: dst[seg][n][k] (bf16) = src[seg][k][oc(n)] (f32)
// 64k x 64n tile; float4 reads (contiguous within 16-col permute groups:
// j%16 in {0,4,8,12} keeps each float4 inside one group), 128B-coalesced writes.
// permute (w1 only): interleave a/b halves in 16-col groups (SwiGLU pairing, 16x16 frags)
__global__ void wt_kernel(const float* __restrict__ srcS, const float* __restrict__ srcR,
                          u16* __restrict__ dst, int K, int N, int permute) {
  __shared__ float tile[64][65];
  const int seg = blockIdx.z;
  const float* src = (seg == 0) ? srcS : srcR + (size_t)(seg - 1) * K * N;
  const int pc0 = blockIdx.x * 64, k0 = blockIdx.y * 64;
  const int tid = threadIdx.x;
  {
    const int kk = tid >> 2;
    const float* srow = src + (size_t)(k0 + kk) * N;
#pragma unroll
    for (int c4 = 0; c4 < 4; ++c4) {
      const int j = (tid & 3) * 4 + c4 * 16;        // j%16 <= 12: float4-safe in 16-group
      const int n = pc0 + j;
      const int oc = permute ? (((n >> 5) << 4) + (n & 15) + ((n & 16) ? FF : 0)) : n;
      const float4 v = *(const float4*)(srow + oc);
      tile[kk][j]     = v.x; tile[kk][j + 1] = v.y;
      tile[kk][j + 2] = v.z; tile[kk][j + 3] = v.w;
    }
  }
  __syncthreads();
  {
    const int c = tid & 7;                          // k-chunk (8 u16)
#pragma unroll
    for (int p = 0; p < 2; ++p) {
      const int pp = p * 32 + (tid >> 3);           // output row (n)
      u16* drow = dst + (size_t)seg * N * K + (size_t)(pc0 + pp) * K + k0;
      uint4 v; unsigned* pv = (unsigned*)&v;
#pragma unroll
      for (int q = 0; q < 4; ++q)
        pv[q] = (unsigned)f2b(tile[c * 8 + 2 * q][pp]) |
                ((unsigned)f2b(tile[c * 8 + 2 * q + 1][pp]) << 16);
      *(uint4*)(drow + c * 8) = v;                  // 8 lanes -> 128B contiguous
    }
  }
}

// ================= 128x128x64 GEMM core — 16x16x32 MFMA, hoisted swizzled reads ======
// 4 waves (2Mx2N), per-wave 64x64 (4x4 frags of 16x16). LDS 32 KiB -> ~4 blocks/CU.
// Read pattern: 2 lanes/bank-slot (fr, fr+8) -> conflict-FREE (R3-measured 0).
// All 16 ds_read addresses loop-invariant (hoisted) -> ~0 per-iter VALU (R4 trick).
// Swizzle byte col ^= (row&7)<<4 both sides (gload source + ds_read).

__device__ __forceinline__ void kloop16(int niter,
    const char* a0, const char* a1, const char* a2, const char* a3,
    const char* b0, const char* b1, const char* b2, const char* b3,
    u16* As, u16* Bs, int tid, f32x4 (&acc)[4][4]) {
  const int lane = tid & 63, fr = lane & 15, kb = (lane >> 4) * 16;
  const int wid = tid >> 6, wm = wid >> 1, wn = wid & 1;
  const int swz = (fr & 7) << 4;
  const char* rA[2][4]; const char* rB[2][4];
#pragma unroll
  for (int ks = 0; ks < 2; ++ks) {        // 2 k-windows of 32 within BK=64
    const int o = (ks * 64 + kb) ^ swz;
#pragma unroll
    for (int q = 0; q < 4; ++q) {
      rA[ks][q] = (const char*)As + (wm * 64 + q * 16 + fr) * 128 + o;
      rB[ks][q] = (const char*)Bs + (wn * 64 + q * 16 + fr) * 128 + o;
    }
  }
  for (int it = 0; it < niter; ++it) {
    const long long kbb = (long long)it * 128;       // 64 u16 per iter
    ldslds16(a0 + kbb, As + tid * 8);
    ldslds16(a1 + kbb, As + 2048 + tid * 8);
    ldslds16(a2 + kbb, As + 4096 + tid * 8);
    ldslds16(a3 + kbb, As + 6144 + tid * 8);
    ldslds16(b0 + kbb, Bs + tid * 8);
    ldslds16(b1 + kbb, Bs + 2048 + tid * 8);
    ldslds16(b2 + kbb, Bs + 4096 + tid * 8);
    ldslds16(b3 + kbb, Bs + 6144 + tid * 8);
    __syncthreads();
#pragma unroll
    for (int ks = 0; ks < 2; ++ks) {
      bf16x8 af[4], bq[4];
#pragma unroll
      for (int q = 0; q < 4; ++q) af[q] = *(const bf16x8*)(rA[ks][q]);
#pragma unroll
      for (int q = 0; q < 4; ++q) bq[q] = *(const bf16x8*)(rB[ks][q]);
#pragma unroll
      for (int mi = 0; mi < 4; ++mi)
#pragma unroll
        for (int ni = 0; ni < 4; ++ni)
          acc[mi][ni] = __builtin_amdgcn_mfma_f32_16x16x32_bf16(af[mi], bq[ni], acc[mi][ni], 0, 0, 0);
    }
    __syncthreads();
  }
}

// map compact g -> (seg, tm, rowstart, rows) scanning counts (no meta buffer)
__device__ __forceinline__ bool seg_map(int g, const int* __restrict__ counts,
                                        int& seg, int& tm, int& rowstart, int& rows) {
  if (g < 64) { seg = 0; tm = g; rowstart = 0; rows = TOK; return true; }
  int gr = g - 64, off = 0;
  for (int e = 0; e < EE; ++e) {
    int c = counts[e];
    int nb = (c + 127) >> 7;
    if (gr < nb) { seg = e + 1; tm = gr; rowstart = off; rows = c; return true; }
    gr -= nb;
    off += (c + 127) & ~127;
  }
  return false;
}

// ---------------- GEMM1: x @ w1t(permuted) -> SwiGLU -> hs bf16 ----------------
__global__ __launch_bounds__(256, 4)
void gemm1_kernel(const u16* __restrict__ xb, const int* __restrict__ s2t,
                  const u16* __restrict__ w1t, const float* __restrict__ sb1,
                  const float* __restrict__ rb1, const int* __restrict__ counts,
                  u16* __restrict__ hs) {
  __shared__ __align__(16) u16 As[128 * 64];
  __shared__ __align__(16) u16 Bs[128 * 64];
  // XCD L2 chunking: same tn -> same lin&7 -> same XCD; B-panel per XCD = 2 MB (L2-fit)
  const int lin = blockIdx.x + 64 * blockIdx.y;
  const int tn = (lin & 7) * 8 + ((lin >> 3) & 7);
  const int g = lin >> 6;
  int seg, tm, rowstart, rows;
  if (!seg_map(g, counts, seg, tm, rowstart, rows)) return;
  const int hsbase = (seg == 0) ? 0 : TOK + rowstart;
  const int tid = threadIdx.x, lane = tid & 63, wid = tid >> 6;
  const int wm = wid >> 1, wn = wid & 1;

  const int srow = tid >> 3;
  const int scol = ((tid & 7) * 16) ^ ((srow & 7) << 4);
  const char* Ac = (const char*)xb;
  const char* Bc = (const char*)(w1t + (size_t)seg * TWOF * DD);
  const char* a[4]; const char* b[4];
#pragma unroll
  for (int r = 0; r < 4; ++r) {
    int rbase = tm * 128 + r * 32 + srow;
    int rg = (seg == 0) ? rbase : s2t[rowstart + rbase];   // pad slots -> token 0
    a[r] = Ac + (size_t)rg * (DD * 2) + scol;
    b[r] = Bc + (size_t)(tn * 128 + r * 32 + srow) * (DD * 2) + scol;
  }

  f32x4 acc[4][4] = {};
  kloop16(DD / 64, a[0], a[1], a[2], a[3], b[0], b[1], b[2], b[3],
          As, Bs, tid, acc);

  const int fr = lane & 15;
  const int rlim = rows - tm * 128;
  const int rb = wm * 64 + (lane >> 4) * 4;
  const float* b1 = (seg == 0) ? sb1 : rb1 + (size_t)(seg - 1) * TWOF;
  u16* hbase = hs + (size_t)(hsbase + tm * 128) * FF;
  const int fc = tn * 64 + wn * 32 + fr;
#pragma unroll
  for (int np = 0; np < 2; ++np) {
    const int f = fc + np * 16;
    const float ba = b1[f], bb = b1[FF + f];
#pragma unroll
    for (int m = 0; m < 4; ++m)
#pragma unroll
      for (int q = 0; q < 4; ++q) {
        int lr = rb + m * 16 + q;
        if (lr < rlim) {
          float av = acc[m][2*np][q] + ba;
          float bv = acc[m][2*np+1][q] + bb;
          float sv = av / (1.0f + __expf(-av)) * bv;
          hbase[(size_t)lr * FF + f] = f2b(sv);
        }
      }
  }
}

// ---------------- GEMM2: hs @ w2t -> yo (bf16, all segments, no atomics) ----------------
__global__ __launch_bounds__(256, 4)
void gemm2_kernel(const u16* __restrict__ hs, const u16* __restrict__ w2t,
                  const float* __restrict__ sb2, const float* __restrict__ rb2,
                  const int* __restrict__ counts, u16* __restrict__ yo) {
  __shared__ __align__(16) u16 As[128 * 64];
  __shared__ __align__(16) u16 Bs[128 * 64];
  const int tn = blockIdx.x;                         // 8 tn -> block lin%8 -> XCD-affine
  const int g = blockIdx.y;
  int seg, tm, rowstart, rows;
  if (!seg_map(g, counts, seg, tm, rowstart, rows)) return;
  const int hrow0 = (seg == 0) ? 0 : TOK + rowstart;
  const int tid = threadIdx.x, lane = tid & 63, wid = tid >> 6;
  const int wm = wid >> 1, wn = wid & 1;

  const int srow = tid >> 3;
  const int scol = ((tid & 7) * 16) ^ ((srow & 7) << 4);
  const char* Ac = (const char*)hs;
  const char* Bc = (const char*)(w2t + (size_t)seg * DD * FF);
  const char* a[4]; const char* b[4];
#pragma unroll
  for (int r = 0; r < 4; ++r) {
    a[r] = Ac + (size_t)(hrow0 + tm * 128 + r * 32 + srow) * (FF * 2) + scol;
    b[r] = Bc + (size_t)(tn * 128 + r * 32 + srow) * (FF * 2) + scol;
  }

  f32x4 acc[4][4] = {};
  kloop16(FF / 64, a[0], a[1], a[2], a[3], b[0], b[1], b[2], b[3],
          As, Bs, tid, acc);

  const int fr = lane & 15;
  const int rlim = rows - tm * 128;
  const int rb = wm * 64 + (lane >> 4) * 4;
  const float* b2 = (seg == 0) ? sb2 : rb2 + (size_t)(seg - 1) * DD;
  const int cc = tn * 128 + wn * 64 + fr;
  float bias[4];
#pragma unroll
  for (int n = 0; n < 4; ++n) bias[n] = b2[cc + n * 16];
  u16* ybase = yo + (size_t)(hrow0 + tm * 128) * DD;
#pragma unroll
  for (int m = 0; m < 4; ++m)
#pragma unroll
    for (int q = 0; q < 4; ++q) {
      int lr = rb + m * 16 + q;
      if (lr >= rlim) continue;
      u16* orow = ybase + (size_t)lr * DD;
#pragma unroll
      for (int n = 0; n < 4; ++n) orow[cc + n * 16] = f2b(acc[m][n][q] + bias[n]);
    }
}

// ---------------- combine: out[t] = yo[t] + w0*yo[T+s0] + w1*yo[T+s1] ----------------
__global__ void combine_kernel(const u16* __restrict__ yo, const int* __restrict__ t2s,
                               const float* __restrict__ ew, float* __restrict__ out) {
  const int t = blockIdx.x, d = threadIdx.x;   // 256 threads x 4 elements
  const int s0 = t2s[2*t], s1 = t2s[2*t+1];
  const float w0 = ew[2*t], w1 = ew[2*t+1];
  const uint2 pa = ((const uint2*)(yo + (size_t)t * DD))[d];
  const uint2 p0 = ((const uint2*)(yo + (size_t)(TOK + s0) * DD))[d];
  const uint2 p1 = ((const uint2*)(yo + (size_t)(TOK + s1) * DD))[d];
  float4 r;
  r.x = b2f((u16)pa.x)         + w0 * b2f((u16)p0.x)         + w1 * b2f((u16)p1.x);
  r.y = b2f((u16)(pa.x >> 16)) + w0 * b2f((u16)(p0.x >> 16)) + w1 * b2f((u16)(p1.x >> 16));
  r.z = b2f((u16)pa.y)         + w0 * b2f((u16)p0.y)         + w1 * b2f((u16)p1.y);
  r.w = b2f((u16)(pa.y >> 16)) + w0 * b2f((u16)(p0.y >> 16)) + w1 * b2f((u16)(p1.y >> 16));
  ((float4*)(out + (size_t)t * DD))[d] = r;
}

// ---------------- launch ----------------
extern "C" void kernel_launch(void* const* d_in, const int* in_sizes, int n_in,
                              void* d_out, int out_size, void* d_ws, size_t ws_size,
                              hipStream_t stream) {
  const float* x   = (const float*)d_in[0];
  const float* gw  = (const float*)d_in[1];
  const float* gb  = (const float*)d_in[2];
  const float* sw1 = (const float*)d_in[3];
  const float* sb1 = (const float*)d_in[4];
  const float* sw2 = (const float*)d_in[5];
  const float* sb2 = (const float*)d_in[6];
  const float* rw1 = (const float*)d_in[7];
  const float* rb1 = (const float*)d_in[8];
  const float* rw2 = (const float*)d_in[9];
  const float* rb2 = (const float*)d_in[10];
  float* out = (float*)d_out;

  char* p = (char*)d_ws;
  auto alloc = [&](size_t bytes) { char* r = p; p += (bytes + 255) & ~(size_t)255; return r; };
  int*   counts = (int*)alloc(EE * 4);
  int*   eidx   = (int*)alloc((size_t)2 * TOK * 4);
  int*   epos   = (int*)alloc((size_t)2 * TOK * 4);
  float* ew     = (float*)alloc((size_t)2 * TOK * 4);
  int*   s2t    = (int*)alloc((size_t)PADT * 4);
  float* swt    = (float*)alloc((size_t)PADT * 4);
  int*   t2s    = (int*)alloc((size_t)2 * TOK * 4);
  u16*   xb     = (u16*)alloc((size_t)TOK * DD * 2);
  u16*   w1t    = (u16*)alloc((size_t)9 * TWOF * DD * 2);
  u16*   w2t    = (u16*)alloc((size_t)9 * DD * FF * 2);
  u16*   hs     = (u16*)alloc((size_t)(TOK + PADT + 128) * FF * 2);
  // yo (bf16) aliases w1t: gemm2 runs strictly after gemm1 (same stream); ~51MB <= 151MB
  u16*   yo     = (u16*)w1t;

  hipMemsetAsync(counts, 0, EE * 4, stream);
  hipMemsetAsync(s2t, 0, (size_t)PADT * 4, stream);
  gate_kernel<<<TOK / 4, 256, 0, stream>>>(x, gw, gb, counts, eidx, epos, ew, xb);
  slot_kernel<<<(2 * TOK) / 256, 256, 0, stream>>>(eidx, epos, ew, counts, s2t, swt, t2s);
  wt_kernel<<<dim3(TWOF / 64, DD / 64, 9), 256, 0, stream>>>(sw1, rw1, w1t, DD, TWOF, 1);
  wt_kernel<<<dim3(DD / 64, FF / 64, 9), 256, 0, stream>>>(sw2, rw2, w2t, FF, DD, 0);
  gemm1_kernel<<<dim3(64, 200), 256, 0, stream>>>(xb, s2t, w1t, sb1, rb1, counts, hs);
  gemm2_kernel<<<dim3(8, 200), 256, 0, stream>>>(hs, w2t, sb2, rb2, counts, yo);
  combine_kernel<<<TOK, 256, 0, stream>>>(yo, t2s, ew, out);
}

// Round 14
// 1062.882 us; speedup vs baseline: 9.8613x; 1.0092x over previous
//
#include <hip/hip_runtime.h>

#define TOK   8192
#define DD    1024
#define FF    4096
#define EE    8
#define TWOF  8192
#define NSLOT 16384   // TOK * top_k(2)
#define PADT  17408   // NSLOT + 8*128 (per-expert 128-row padding bound)

typedef unsigned short u16;
typedef float  f32x4  __attribute__((ext_vector_type(4)));
typedef __bf16 bf16x8 __attribute__((ext_vector_type(8)));

__device__ __forceinline__ u16 f2b(float f) {
  unsigned u = __builtin_bit_cast(unsigned, f);
  u += 0x7fffu + ((u >> 16) & 1u);   // RNE; inputs finite
  return (u16)(u >> 16);
}

__device__ __forceinline__ float b2f(u16 b) {
  return __builtin_bit_cast(float, (unsigned)b << 16);
}

__device__ __forceinline__ void ldslds16(const void* g, void* l) {
  __builtin_amdgcn_global_load_lds((const __attribute__((address_space(1))) void*)g,
                                   (__attribute__((address_space(3))) void*)l, 16, 0, 0);
}

// ---------------- gate (+x->bf16 convert fused, +s2t zeroing): logits, softmax, top-2 ----
__global__ void gate_kernel(const float* __restrict__ x, const float* __restrict__ gw,
                            const float* __restrict__ gb, int* __restrict__ counts,
                            int* __restrict__ eidx, int* __restrict__ epos,
                            float* __restrict__ ew, u16* __restrict__ xb,
                            int* __restrict__ s2t) {
  // fused s2t zeroing: 68 blocks x 256 ints == PADT; completes before slot (stream order)
  if (blockIdx.x < PADT / 256) s2t[blockIdx.x * 256 + threadIdx.x] = 0;
  const int wave = threadIdx.x >> 6, lane = threadIdx.x & 63;
  const int t = blockIdx.x * 4 + wave;
  float acc[EE] = {0,0,0,0,0,0,0,0};
  const float* xr = x + (size_t)t * DD;
  u16* xbr = xb + (size_t)t * DD;
#pragma unroll
  for (int i = 0; i < DD / 256; ++i) {              // 4 float4-iters
    const int f = i * 64 + lane;                    // float4 index
    const float4 v = ((const float4*)xr)[f];
    const int d = f * 4;
    const float* g = gw + (size_t)d * EE;
#pragma unroll
    for (int e = 0; e < EE; ++e)
      acc[e] += v.x * g[e] + v.y * g[EE + e] + v.z * g[2 * EE + e] + v.w * g[3 * EE + e];
    uint2 pk;
    pk.x = (unsigned)f2b(v.x) | ((unsigned)f2b(v.y) << 16);
    pk.y = (unsigned)f2b(v.z) | ((unsigned)f2b(v.w) << 16);
    ((uint2*)xbr)[f] = pk;
  }
#pragma unroll
  for (int e = 0; e < EE; ++e)
#pragma unroll
    for (int off = 32; off > 0; off >>= 1) acc[e] += __shfl_down(acc[e], off);
  if (lane == 0) {
    float l[EE];
#pragma unroll
    for (int e = 0; e < EE; ++e) l[e] = acc[e] + gb[e];
    int i0 = 0;
    for (int e = 1; e < EE; ++e) if (l[e] > l[i0]) i0 = e;
    int i1 = (i0 == 0) ? 1 : 0;
    for (int e = 0; e < EE; ++e) { if (e == i0) continue; if (l[e] > l[i1]) i1 = e; }
    float m = l[0];
    for (int e = 1; e < EE; ++e) m = fmaxf(m, l[e]);
    float s = 0.f, p[EE];
    for (int e = 0; e < EE; ++e) { p[e] = __expf(l[e] - m); s += p[e]; }
    float w0 = p[i0] / s, w1 = p[i1] / s;
    int p0 = atomicAdd(&counts[i0], 1);
    int p1 = atomicAdd(&counts[i1], 1);
    eidx[2*t] = i0; eidx[2*t+1] = i1;
    epos[2*t] = p0; epos[2*t+1] = p1;
    ew[2*t] = w0;  ew[2*t+1] = w1;
  }
}

// slot: inline 128-aligned prefix over counts (8 ints, L2-hot)
__global__ void slot_kernel(const int* __restrict__ eidx, const int* __restrict__ epos,
                            const float* __restrict__ ew, const int* __restrict__ counts,
                            int* __restrict__ s2t, float* __restrict__ swt,
                            int* __restrict__ t2s) {
  int i = blockIdx.x * 256 + threadIdx.x;           // 0..2T-1
  int e = eidx[i];
  int off = 0;
  for (int j = 0; j < e; ++j) off += (counts[j] + 127) & ~127;
  int slot = off + epos[i];
  s2t[slot] = i >> 1;
  swt[slot] = ew[i];
  t2s[i] = slot;
}

// transpose-convert weights (merged w1+w2 in one flat-grid launch):
// dst[seg][n][k] (bf16) = src[seg][k][oc(n)] (f32). 64x64 tiles; float4 reads
// (contiguous within 16-col permute groups), 128B-coalesced uint4 writes.
// blocks [0, 18432): w1 (permuted, K=DD, N=TWOF); [18432, 27648): w2 (K=FF, N=DD).
__global__ void wt_kernel(const float* __restrict__ sw1, const float* __restrict__ rw1,
                          const float* __restrict__ sw2, const float* __restrict__ rw2,
                          u16* __restrict__ w1t, u16* __restrict__ w2t) {
  __shared__ float tile[64][65];
  const int bid = blockIdx.x;
  const float* srcS; const float* srcR; u16* dst;
  int seg, pc0, k0, K, N, permute;
  if (bid < 18432) {                                // w1: 9 segs x (128 x 16) tiles
    seg = bid / 2048; int rem = bid % 2048;
    pc0 = (rem & 127) * 64; k0 = (rem >> 7) * 64;
    srcS = sw1; srcR = rw1; dst = w1t; K = DD; N = TWOF; permute = 1;
  } else {                                          // w2: 9 segs x (16 x 64) tiles
    int b2 = bid - 18432;
    seg = b2 / 1024; int rem = b2 % 1024;
    pc0 = (rem & 15) * 64; k0 = (rem >> 4) * 64;
    srcS = sw2; srcR = rw2; dst = w2t; K = FF; N = DD; permute = 0;
  }
  const float* src = (seg == 0) ? srcS : srcR + (size_t)(seg - 1) * K * N;
  const int tid = threadIdx.x;
  {
    const int kk = tid >> 2;
    const float* srow = src + (size_t)(k0 + kk) * N;
#pragma unroll
    for (int c4 = 0; c4 < 4; ++c4) {
      const int j = (tid & 3) * 4 + c4 * 16;        // j%16 <= 12: float4-safe in 16-group
      const int n = pc0 + j;
      const int oc = permute ? (((n >> 5) << 4) + (n & 15) + ((n & 16) ? FF : 0)) : n;
      const float4 v = *(const float4*)(srow + oc);
      tile[kk][j]     = v.x; tile[kk][j + 1] = v.y;
      tile[kk][j + 2] = v.z; tile[kk][j + 3] = v.w;
    }
  }
  __syncthreads();
  {
    const int c = tid & 7;                          // k-chunk (8 u16)
#pragma unroll
    for (int p = 0; p < 2; ++p) {
      const int pp = p * 32 + (tid >> 3);           // output row (n)
      u16* drow = dst + (size_t)seg * N * K + (size_t)(pc0 + pp) * K + k0;
      uint4 v; unsigned* pv = (unsigned*)&v;
#pragma unroll
      for (int q = 0; q < 4; ++q)
        pv[q] = (unsigned)f2b(tile[c * 8 + 2 * q][pp]) |
                ((unsigned)f2b(tile[c * 8 + 2 * q + 1][pp]) << 16);
      *(uint4*)(drow + c * 8) = v;                  // 8 lanes -> 128B contiguous
    }
  }
}

// ================= 128x128x64 GEMM core — 16x16x32 MFMA, hoisted swizzled reads ======
// 4 waves (2Mx2N), per-wave 64x64 (4x4 frags of 16x16). LDS 32 KiB -> ~4 blocks/CU.
// Read pattern: 2 lanes/bank-slot -> conflict-FREE (R13-measured 0).
// All 16 ds_read addresses loop-invariant (hoisted) -> ~0 per-iter VALU.
// Swizzle byte col ^= (row&7)<<4 both sides (gload source + ds_read).

__device__ __forceinline__ void kloop16(int niter,
    const char* a0, const char* a1, const char* a2, const char* a3,
    const char* b0, const char* b1, const char* b2, const char* b3,
    u16* As, u16* Bs, int tid, f32x4 (&acc)[4][4]) {
  const int lane = tid & 63, fr = lane & 15, kb = (lane >> 4) * 16;
  const int wid = tid >> 6, wm = wid >> 1, wn = wid & 1;
  const int swz = (fr & 7) << 4;
  const char* rA[2][4]; const char* rB[2][4];
#pragma unroll
  for (int ks = 0; ks < 2; ++ks) {        // 2 k-windows of 32 within BK=64
    const int o = (ks * 64 + kb) ^ swz;
#pragma unroll
    for (int q = 0; q < 4; ++q) {
      rA[ks][q] = (const char*)As + (wm * 64 + q * 16 + fr) * 128 + o;
      rB[ks][q] = (const char*)Bs + (wn * 64 + q * 16 + fr) * 128 + o;
    }
  }
  for (int it = 0; it < niter; ++it) {
    const long long kbb = (long long)it * 128;       // 64 u16 per iter
    ldslds16(a0 + kbb, As + tid * 8);
    ldslds16(a1 + kbb, As + 2048 + tid * 8);
    ldslds16(a2 + kbb, As + 4096 + tid * 8);
    ldslds16(a3 + kbb, As + 6144 + tid * 8);
    ldslds16(b0 + kbb, Bs + tid * 8);
    ldslds16(b1 + kbb, Bs + 2048 + tid * 8);
    ldslds16(b2 + kbb, Bs + 4096 + tid * 8);
    ldslds16(b3 + kbb, Bs + 6144 + tid * 8);
    __syncthreads();
#pragma unroll
    for (int ks = 0; ks < 2; ++ks) {
      bf16x8 af[4], bq[4];
#pragma unroll
      for (int q = 0; q < 4; ++q) af[q] = *(const bf16x8*)(rA[ks][q]);
#pragma unroll
      for (int q = 0; q < 4; ++q) bq[q] = *(const bf16x8*)(rB[ks][q]);
#pragma unroll
      for (int mi = 0; mi < 4; ++mi)
#pragma unroll
        for (int ni = 0; ni < 4; ++ni)
          acc[mi][ni] = __builtin_amdgcn_mfma_f32_16x16x32_bf16(af[mi], bq[ni], acc[mi][ni], 0, 0, 0);
    }
    __syncthreads();
  }
}

// map compact g -> (seg, tm, rowstart, rows) scanning counts (no meta buffer)
__device__ __forceinline__ bool seg_map(int g, const int* __restrict__ counts,
                                        int& seg, int& tm, int& rowstart, int& rows) {
  if (g < 64) { seg = 0; tm = g; rowstart = 0; rows = TOK; return true; }
  int gr = g - 64, off = 0;
  for (int e = 0; e < EE; ++e) {
    int c = counts[e];
    int nb = (c + 127) >> 7;
    if (gr < nb) { seg = e + 1; tm = gr; rowstart = off; rows = c; return true; }
    gr -= nb;
    off += (c + 127) & ~127;
  }
  return false;
}

// ---------------- GEMM1: x @ w1t(permuted) -> SwiGLU -> hs bf16 ----------------
__global__ __launch_bounds__(256, 4)
void gemm1_kernel(const u16* __restrict__ xb, const int* __restrict__ s2t,
                  const u16* __restrict__ w1t, const float* __restrict__ sb1,
                  const float* __restrict__ rb1, const int* __restrict__ counts,
                  u16* __restrict__ hs) {
  __shared__ __align__(16) u16 As[128 * 64];
  __shared__ __align__(16) u16 Bs[128 * 64];
  // XCD L2 chunking: same tn -> same lin&7 -> same XCD; B-panel per XCD = 2 MB (L2-fit)
  const int lin = blockIdx.x + 64 * blockIdx.y;
  const int tn = (lin & 7) * 8 + ((lin >> 3) & 7);
  const int g = lin >> 6;
  int seg, tm, rowstart, rows;
  if (!seg_map(g, counts, seg, tm, rowstart, rows)) return;
  const int hsbase = (seg == 0) ? 0 : TOK + rowstart;
  const int tid = threadIdx.x, lane = tid & 63, wid = tid >> 6;
  const int wm = wid >> 1, wn = wid & 1;

  const int srow = tid >> 3;
  const int scol = ((tid & 7) * 16) ^ ((srow & 7) << 4);
  const char* Ac = (const char*)xb;
  const char* Bc = (const char*)(w1t + (size_t)seg * TWOF * DD);
  const char* a[4]; const char* b[4];
#pragma unroll
  for (int r = 0; r < 4; ++r) {
    int rbase = tm * 128 + r * 32 + srow;
    int rg = (seg == 0) ? rbase : s2t[rowstart + rbase];   // pad slots -> token 0
    a[r] = Ac + (size_t)rg * (DD * 2) + scol;
    b[r] = Bc + (size_t)(tn * 128 + r * 32 + srow) * (DD * 2) + scol;
  }

  f32x4 acc[4][4] = {};
  kloop16(DD / 64, a[0], a[1], a[2], a[3], b[0], b[1], b[2], b[3],
          As, Bs, tid, acc);

  const int fr = lane & 15;
  const int rlim = rows - tm * 128;
  const int rb = wm * 64 + (lane >> 4) * 4;
  const float* b1 = (seg == 0) ? sb1 : rb1 + (size_t)(seg - 1) * TWOF;
  u16* hbase = hs + (size_t)(hsbase + tm * 128) * FF;
  const int fc = tn * 64 + wn * 32 + fr;
#pragma unroll
  for (int np = 0; np < 2; ++np) {
    const int f = fc + np * 16;
    const float ba = b1[f], bb = b1[FF + f];
#pragma unroll
    for (int m = 0; m < 4; ++m)
#pragma unroll
      for (int q = 0; q < 4; ++q) {
        int lr = rb + m * 16 + q;
        if (lr < rlim) {
          float av = acc[m][2*np][q] + ba;
          float bv = acc[m][2*np+1][q] + bb;
          float sv = av / (1.0f + __expf(-av)) * bv;
          hbase[(size_t)lr * FF + f] = f2b(sv);
        }
      }
  }
}

// ---------------- GEMM2: hs @ w2t -> yo (bf16, all segments, no atomics) ----------------
__global__ __launch_bounds__(256, 4)
void gemm2_kernel(const u16* __restrict__ hs, const u16* __restrict__ w2t,
                  const float* __restrict__ sb2, const float* __restrict__ rb2,
                  const int* __restrict__ counts, u16* __restrict__ yo) {
  __shared__ __align__(16) u16 As[128 * 64];
  __shared__ __align__(16) u16 Bs[128 * 64];
  const int tn = blockIdx.x;                         // 8 tn -> block lin%8 -> XCD-affine
  const int g = blockIdx.y;
  int seg, tm, rowstart, rows;
  if (!seg_map(g, counts, seg, tm, rowstart, rows)) return;
  const int hrow0 = (seg == 0) ? 0 : TOK + rowstart;
  const int tid = threadIdx.x, lane = tid & 63, wid = tid >> 6;
  const int wm = wid >> 1, wn = wid & 1;

  const int srow = tid >> 3;
  const int scol = ((tid & 7) * 16) ^ ((srow & 7) << 4);
  const char* Ac = (const char*)hs;
  const char* Bc = (const char*)(w2t + (size_t)seg * DD * FF);
  const char* a[4]; const char* b[4];
#pragma unroll
  for (int r = 0; r < 4; ++r) {
    a[r] = Ac + (size_t)(hrow0 + tm * 128 + r * 32 + srow) * (FF * 2) + scol;
    b[r] = Bc + (size_t)(tn * 128 + r * 32 + srow) * (FF * 2) + scol;
  }

  f32x4 acc[4][4] = {};
  kloop16(FF / 64, a[0], a[1], a[2], a[3], b[0], b[1], b[2], b[3],
          As, Bs, tid, acc);

  const int fr = lane & 15;
  const int rlim = rows - tm * 128;
  const int rb = wm * 64 + (lane >> 4) * 4;
  const float* b2 = (seg == 0) ? sb2 : rb2 + (size_t)(seg - 1) * DD;
  const int cc = tn * 128 + wn * 64 + fr;
  float bias[4];
#pragma unroll
  for (int n = 0; n < 4; ++n) bias[n] = b2[cc + n * 16];
  u16* ybase = yo + (size_t)(hrow0 + tm * 128) * DD;
#pragma unroll
  for (int m = 0; m < 4; ++m)
#pragma unroll
    for (int q = 0; q < 4; ++q) {
      int lr = rb + m * 16 + q;
      if (lr >= rlim) continue;
      u16* orow = ybase + (size_t)lr * DD;
#pragma unroll
      for (int n = 0; n < 4; ++n) orow[cc + n * 16] = f2b(acc[m][n][q] + bias[n]);
    }
}

// ---------------- combine: out[t] = yo[t] + w0*yo[T+s0] + w1*yo[T+s1] ----------------
__global__ void combine_kernel(const u16* __restrict__ yo, const int* __restrict__ t2s,
                               const float* __restrict__ ew, float* __restrict__ out) {
  const int d = threadIdx.x;                   // 256 threads x 4 elements, 4 tokens/block
#pragma unroll
  for (int k = 0; k < 4; ++k) {
    const int t = blockIdx.x * 4 + k;
    const int s0 = t2s[2*t], s1 = t2s[2*t+1];
    const float w0 = ew[2*t], w1 = ew[2*t+1];
    const uint2 pa = ((const uint2*)(yo + (size_t)t * DD))[d];
    const uint2 p0 = ((const uint2*)(yo + (size_t)(TOK + s0) * DD))[d];
    const uint2 p1 = ((const uint2*)(yo + (size_t)(TOK + s1) * DD))[d];
    float4 r;
    r.x = b2f((u16)pa.x)         + w0 * b2f((u16)p0.x)         + w1 * b2f((u16)p1.x);
    r.y = b2f((u16)(pa.x >> 16)) + w0 * b2f((u16)(p0.x >> 16)) + w1 * b2f((u16)(p1.x >> 16));
    r.z = b2f((u16)pa.y)         + w0 * b2f((u16)p0.y)         + w1 * b2f((u16)p1.y);
    r.w = b2f((u16)(pa.y >> 16)) + w0 * b2f((u16)(p0.y >> 16)) + w1 * b2f((u16)(p1.y >> 16));
    ((float4*)(out + (size_t)t * DD))[d] = r;
  }
}

// ---------------- launch ----------------
extern "C" void kernel_launch(void* const* d_in, const int* in_sizes, int n_in,
                              void* d_out, int out_size, void* d_ws, size_t ws_size,
                              hipStream_t stream) {
  const float* x   = (const float*)d_in[0];
  const float* gw  = (const float*)d_in[1];
  const float* gb  = (const float*)d_in[2];
  const float* sw1 = (const float*)d_in[3];
  const float* sb1 = (const float*)d_in[4];
  const float* sw2 = (const float*)d_in[5];
  const float* sb2 = (const float*)d_in[6];
  const float* rw1 = (const float*)d_in[7];
  const float* rb1 = (const float*)d_in[8];
  const float* rw2 = (const float*)d_in[9];
  const float* rb2 = (const float*)d_in[10];
  float* out = (float*)d_out;

  char* p = (char*)d_ws;
  auto alloc = [&](size_t bytes) { char* r = p; p += (bytes + 255) & ~(size_t)255; return r; };
  int*   counts = (int*)alloc(EE * 4);
  int*   eidx   = (int*)alloc((size_t)2 * TOK * 4);
  int*   epos   = (int*)alloc((size_t)2 * TOK * 4);
  float* ew     = (float*)alloc((size_t)2 * TOK * 4);
  int*   s2t    = (int*)alloc((size_t)PADT * 4);
  float* swt    = (float*)alloc((size_t)PADT * 4);
  int*   t2s    = (int*)alloc((size_t)2 * TOK * 4);
  u16*   xb     = (u16*)alloc((size_t)TOK * DD * 2);
  u16*   w1t    = (u16*)alloc((size_t)9 * TWOF * DD * 2);
  u16*   w2t    = (u16*)alloc((size_t)9 * DD * FF * 2);
  u16*   hs     = (u16*)alloc((size_t)(TOK + PADT + 128) * FF * 2);
  // yo (bf16) aliases w1t: gemm2 runs strictly after gemm1 (same stream); ~51MB <= 151MB
  u16*   yo     = (u16*)w1t;

  hipMemsetAsync(counts, 0, EE * 4, stream);
  gate_kernel<<<TOK / 4, 256, 0, stream>>>(x, gw, gb, counts, eidx, epos, ew, xb, s2t);
  slot_kernel<<<(2 * TOK) / 256, 256, 0, stream>>>(eidx, epos, ew, counts, s2t, swt, t2s);
  wt_kernel<<<27648, 256, 0, stream>>>(sw1, rw1, sw2, rw2, w1t, w2t);
  gemm1_kernel<<<dim3(64, 200), 256, 0, stream>>>(xb, s2t, w1t, sb1, rb1, counts, hs);
  gemm2_kernel<<<dim3(8, 200), 256, 0, stream>>>(hs, w2t, sb2, rb2, counts, yo);
  combine_kernel<<<TOK / 4, 256, 0, stream>>>(yo, t2s, ew, out);
}